// Round 8
// baseline (364.912 us; speedup 1.0000x reference)
//
#include <hip/hip_runtime.h>
#include <hip/hip_bf16.h>
#include <math.h>

#define NB 32768      // total nodes (B*N)
#define NN 2048       // nodes per graph
#define BG 16         // graphs
#define KK 1639       // kept per graph
#define N1 (BG*KK)    // 26224 kept nodes total
#define EE 524288     // total edges
#define HH 128        // hidden
#define FIN 64        // input features
#define SLICES 16

using half8 = __attribute__((ext_vector_type(8))) _Float16;
using f32x4 = __attribute__((ext_vector_type(4))) float;

// ---------------- CSR build ----------------
__global__ void deg_kernel(const int* __restrict__ dst, int* deg, int n) {
  int e = blockIdx.x * blockDim.x + threadIdx.x;
  if (e < n) atomicAdd(&deg[dst[e]], 1);
}

__global__ void deg2_kernel(const int* __restrict__ src, const int* __restrict__ dst,
                            const int* __restrict__ new_id, int* deg, int n) {
  int e = blockIdx.x * blockDim.x + threadIdx.x;
  if (e < n) {
    int a = new_id[src[e]], d = new_id[dst[e]];
    if (a >= 0 && d >= 0) atomicAdd(&deg[d], 1);
  }
}

// single-block coalesced exclusive scan over tiles of 4096 (int4/lane);
// writes rs[0..n] and cursor[0..n-1]. Caller must pad deg so int4 reads up to
// ceil(n/4096)*4096 stay in-bounds.
__global__ void exscan_kernel(const int* __restrict__ deg, int* rs, int* cursor, int n) {
  __shared__ int wsum[16];
  __shared__ int carry;
  int t = threadIdx.x;  // 1024
  int lane = t & 63, wid = t >> 6;
  if (t == 0) carry = 0;
  __syncthreads();
  int ntiles = (n + 4095) >> 12;
  for (int tile = 0; tile < ntiles; ++tile) {
    int idx = (tile << 12) + t * 4;
    int4 v4 = *(const int4*)(deg + idx);  // coalesced 16B/lane (padded alloc)
    int v0 = (idx + 0 < n) ? v4.x : 0;
    int v1 = (idx + 1 < n) ? v4.y : 0;
    int v2 = (idx + 2 < n) ? v4.z : 0;
    int v3 = (idx + 3 < n) ? v4.w : 0;
    int s = v0 + v1 + v2 + v3;
    int pre = s;
#pragma unroll
    for (int off = 1; off < 64; off <<= 1) {
      int u = __shfl_up(pre, off, 64);
      if (lane >= off) pre += u;
    }
    if (lane == 63) wsum[wid] = pre;
    __syncthreads();
    int wbase = 0;
#pragma unroll
    for (int ww = 0; ww < 16; ++ww)
      if (ww < wid) wbase += wsum[ww];
    int ex = carry + wbase + (pre - s);
    int4 e4 = make_int4(ex, ex + v0, ex + v0 + v1, ex + v0 + v1 + v2);
    if (idx + 3 < n) {
      *(int4*)(rs + idx) = e4;
      *(int4*)(cursor + idx) = e4;
    } else {
      if (idx + 0 < n) { rs[idx + 0] = e4.x; cursor[idx + 0] = e4.x; }
      if (idx + 1 < n) { rs[idx + 1] = e4.y; cursor[idx + 1] = e4.y; }
      if (idx + 2 < n) { rs[idx + 2] = e4.z; cursor[idx + 2] = e4.z; }
    }
    int tot = 0;
    if (t == 1023) tot = ex + s;
    __syncthreads();            // all carry-reads done before update
    if (t == 1023) carry = tot;
    __syncthreads();
  }
  if (t == 0) rs[n] = carry;
}

__global__ void scatter_kernel(const int* __restrict__ src, const int* __restrict__ dst,
                               int* cursor, int* csr, int n) {
  int e = blockIdx.x * blockDim.x + threadIdx.x;
  if (e < n) {
    int d = dst[e];
    int p = atomicAdd(&cursor[d], 1);
    csr[p] = src[e];
  }
}

__global__ void scatter2_kernel(const int* __restrict__ src, const int* __restrict__ dst,
                                const int* __restrict__ new_id, int* cursor, int* csr, int n) {
  int e = blockIdx.x * blockDim.x + threadIdx.x;
  if (e < n) {
    int a = new_id[src[e]], d = new_id[dst[e]];
    if (a >= 0 && d >= 0) {
      int p = atomicAdd(&cursor[d], 1);
      csr[p] = a;
    }
  }
}

// ---------------- fused agg + conv GEMM via f16 split-precision MFMA ----------------
// out = relu([agg|x] @ Wcat^T + b), agg gathered in-kernel from CSR.
// Block: 512 thr = 8 waves; tile = 64 rows x 128 cols; wave = 64x16 (4 row-frags).
// Phase 1: W preload (reg-stationary, full K) + per-row CSR gather (KD1/16 threads
//   per row, 4 f32x4 accumulators = ILP 4) + root staging; both convert f32 ->
//   f16 hi/lo into XOR-swizzled LDS planes.
// Phase 2: k-loop = ds_read + MFMA only (3-product split-precision, err ~2^-22).
// XCD-swizzled grid (bijective m204) for gather L2 locality.
template <int KD1, int KD2>
__global__ __launch_bounds__(512, 4) void conv_mfma(
    const float* __restrict__ feat, const float* __restrict__ xr,
    const int* __restrict__ rs, const int* __restrict__ csr,
    const _Float16* __restrict__ Wh, const _Float16* __restrict__ Wl,
    const float* __restrict__ bias, float* __restrict__ out, int M, int nwg) {
  constexpr int KTOT = KD1 + KD2;
  constexpr int NSTEP = KTOT / 32;
  constexpr int TPR = KD1 / 16;  // threads per row for gather (4 or 8)
  __shared__ _Float16 ah_lds[64 * KTOT];
  __shared__ _Float16 al_lds[64 * KTOT];

  int tid = threadIdx.x;
  int lane = tid & 63, wid = tid >> 6;
  // bijective XCD-chunk swizzle (m204)
  int bq = nwg >> 3, br = nwg & 7, bx = blockIdx.x & 7, bi = blockIdx.x >> 3;
  int swz = (bx < br ? bx * (bq + 1) : br * (bq + 1) + (bx - br) * bq) + bi;
  int row0 = swz * 64;
  int ch0 = wid * 16;           // 8 waves cover the 128 output cols
  int col = lane & 15;
  int kseg = (lane >> 4) * 8;

  // ---- W preload: full-K B fragments into registers (issued first, overlaps gather)
  half8 wh_r[NSTEP], wl_r[NSTEP];
#pragma unroll
  for (int s = 0; s < NSTEP; ++s) {
    size_t wof = (size_t)(ch0 + col) * KTOT + s * 32 + kseg;
    wh_r[s] = *(const half8*)(Wh + wof);
    wl_r[s] = *(const half8*)(Wl + wof);
  }

  // ---- Phase 1a: CSR gather for agg half (k in [0, KD1)) ----
  {
    int gr = tid / TPR;         // row within tile
    int gj = tid % TPR;         // 16-col chunk within row
    if (gr < 64) {
      int grow = row0 + gr;
      if (grow >= M) grow = M - 1;  // clamp (dup work, stores guarded)
      const float4* fbase = (const float4*)feat + gj * 4;
      int e0 = rs[grow], e1 = rs[grow + 1];
      f32x4 s0 = {0.f, 0.f, 0.f, 0.f}, s1 = s0, s2 = s0, s3 = s0;
      for (int e = e0; e < e1; ++e) {
        const float4* fp = fbase + (size_t)csr[e] * (KD1 / 4);
        float4 v0 = fp[0], v1 = fp[1], v2 = fp[2], v3 = fp[3];
        s0 += (f32x4){v0.x, v0.y, v0.z, v0.w};
        s1 += (f32x4){v1.x, v1.y, v1.z, v1.w};
        s2 += (f32x4){v2.x, v2.y, v2.z, v2.w};
        s3 += (f32x4){v3.x, v3.y, v3.z, v3.w};
      }
      float sv[16] = {s0[0], s0[1], s0[2], s0[3], s1[0], s1[1], s1[2], s1[3],
                      s2[0], s2[1], s2[2], s2[3], s3[0], s3[1], s3[2], s3[3]};
      half8 vh[2], vl[2];
#pragma unroll
      for (int j = 0; j < 16; ++j) {
        _Float16 h = (_Float16)sv[j];
        vh[j >> 3][j & 7] = h;
        vl[j >> 3][j & 7] = (_Float16)(sv[j] - (float)h);
      }
      int base = (gr * KTOT + gj * 16) * 2;
      int sw = (gr & 7) << 4;
#pragma unroll
      for (int half = 0; half < 2; ++half) {
        int byte = (base + half * 16) ^ sw;
        *(half8*)((char*)ah_lds + byte) = vh[half];
        *(half8*)((char*)al_lds + byte) = vl[half];
      }
    }
  }

  // ---- Phase 1b: root staging (k in [KD1, KTOT)) ----
  for (int idx = tid; idx < 64 * KD2 / 8; idx += 512) {
    int row = idx / (KD2 / 8);
    int kc = (idx % (KD2 / 8)) * 8;
    int grow = row0 + row;
    if (grow >= M) grow = M - 1;
    const float* sp = xr + (size_t)grow * KD2 + kc;
    float4 a0 = *(const float4*)sp;
    float4 a1 = *(const float4*)(sp + 4);
    float av[8] = {a0.x, a0.y, a0.z, a0.w, a1.x, a1.y, a1.z, a1.w};
    half8 vh, vl;
#pragma unroll
    for (int j = 0; j < 8; ++j) {
      _Float16 h = (_Float16)av[j];
      vh[j] = h;
      vl[j] = (_Float16)(av[j] - (float)h);
    }
    int byte = ((row * KTOT + KD1 + kc) * 2) ^ ((row & 7) << 4);
    *(half8*)((char*)ah_lds + byte) = vh;
    *(half8*)((char*)al_lds + byte) = vl;
  }
  __syncthreads();

  // ---- Phase 2: k-loop, pure ds_read + MFMA ----
  f32x4 acc[4];
#pragma unroll
  for (int rf = 0; rf < 4; ++rf) acc[rf] = (f32x4){0.f, 0.f, 0.f, 0.f};
  int r = lane & 15;
#pragma unroll
  for (int s = 0; s < NSTEP; ++s) {
#pragma unroll
    for (int rf = 0; rf < 4; ++rf) {
      int row = rf * 16 + r;
      int byte = ((row * KTOT + s * 32 + kseg) * 2) ^ ((row & 7) << 4);
      half8 a_h = *(const half8*)((const char*)ah_lds + byte);
      half8 a_l = *(const half8*)((const char*)al_lds + byte);
      acc[rf] = __builtin_amdgcn_mfma_f32_16x16x32_f16(a_l, wh_r[s], acc[rf], 0, 0, 0);
      acc[rf] = __builtin_amdgcn_mfma_f32_16x16x32_f16(a_h, wl_r[s], acc[rf], 0, 0, 0);
      acc[rf] = __builtin_amdgcn_mfma_f32_16x16x32_f16(a_h, wh_r[s], acc[rf], 0, 0, 0);
    }
  }

  // ---- epilogue: bias + relu; C/D map col=lane&15, row=(lane>>4)*4+reg ----
  float bv = bias[ch0 + col];
#pragma unroll
  for (int rf = 0; rf < 4; ++rf) {
    int orow0 = row0 + rf * 16 + (lane >> 4) * 4;
#pragma unroll
    for (int rr = 0; rr < 4; ++rr) {
      int orow = orow0 + rr;
      if (orow < M) out[(size_t)orow * HH + ch0 + col] = fmaxf(acc[rf][rr] + bv, 0.f);
    }
  }
}

// ---------------- weight prep: split Wcat[o][k] into f16 hi + lo planes ----------------
__global__ void prep_weights_f16(const float* __restrict__ W1_rel, const float* __restrict__ W1_root,
                                 const float* __restrict__ W2_rel, const float* __restrict__ W2_root,
                                 const float* __restrict__ W3_rel, const float* __restrict__ W3_root,
                                 _Float16* wh1, _Float16* wl1, _Float16* wh2, _Float16* wl2,
                                 _Float16* wh3, _Float16* wl3) {
  int idx = blockIdx.x * blockDim.x + threadIdx.x;
  float v;
  _Float16* ph;
  _Float16* pl;
  int j;
  if (idx < 128 * 128) {
    j = idx;
    int o = j >> 7, k = j & 127;
    v = (k < 64) ? W1_rel[o * 64 + k] : W1_root[o * 64 + (k - 64)];
    ph = wh1; pl = wl1;
  } else if (idx < 128 * 128 + 128 * 256) {
    j = idx - 128 * 128;
    int o = j >> 8, k = j & 255;
    v = (k < 128) ? W2_rel[o * 128 + k] : W2_root[o * 128 + (k - 128)];
    ph = wh2; pl = wl2;
  } else if (idx < 128 * 128 + 2 * 128 * 256) {
    j = idx - 128 * 128 - 128 * 256;
    int o = j >> 8, k = j & 255;
    v = (k < 128) ? W3_rel[o * 128 + k] : W3_root[o * 128 + (k - 128)];
    ph = wh3; pl = wl3;
  } else {
    return;
  }
  _Float16 h = (_Float16)v;
  ph[j] = h;
  pl[j] = (_Float16)(v - (float)h);
}

// ---------------- pooling partials ----------------
__global__ void pool_partial_kernel(const float* __restrict__ h, int rows_per_graph,
                                    float* pmax, float* psum) {
  int b = blockIdx.x / SLICES, s = blockIdx.x % SLICES;
  int f = threadIdx.x;
  int per = (rows_per_graph + SLICES - 1) / SLICES;
  int r0 = s * per, r1 = min(rows_per_graph, r0 + per);
  float m = -3.402823466e38f, sum = 0.f;
  for (int r = r0; r < r1; ++r) {
    float v = h[(size_t)(b * rows_per_graph + r) * HH + f];
    m = fmaxf(m, v);
    sum += v;
  }
  pmax[(b * SLICES + s) * HH + f] = m;
  psum[(b * SLICES + s) * HH + f] = sum;
}

// ---------------- scoring (norm fused per-wave) ----------------
__global__ void score_kernel(const float* __restrict__ h2, const float* __restrict__ w,
                             float* score, int M) {
  int wave = threadIdx.x >> 6;
  int lane = threadIdx.x & 63;
  int i = blockIdx.x * (blockDim.x >> 6) + wave;
  if (i >= M) return;
  float wl0 = w[lane], wl1 = w[64 + lane];
  float acc = h2[i * HH + lane] * wl0 + h2[i * HH + 64 + lane] * wl1;
  float nsq = wl0 * wl0 + wl1 * wl1;
  for (int off = 32; off > 0; off >>= 1) {
    acc += __shfl_down(acc, off, 64);
    nsq += __shfl_down(nsq, off, 64);
  }
  if (lane == 0) score[i] = tanhf(acc / sqrtf(nsq));
}

// per-graph bitonic sort of 2048 (score,index) keys; keep top K, tie-break lowest index
__global__ void topk_kernel(const float* __restrict__ score, int* perm) {
  __shared__ unsigned long long k[NN];
  int b = blockIdx.x;
  int tid = threadIdx.x;  // 1024
  for (int i = tid; i < NN; i += 1024) {
    float s = score[b * NN + i];
    unsigned u = __float_as_uint(s);
    u = (u & 0x80000000u) ? ~u : (u | 0x80000000u);
    unsigned long long key = ((unsigned long long)u << 32) | (unsigned)(NN - 1 - i);
    k[i] = ~key;  // ascending sort of ~key == descending by (score, -index)
  }
  __syncthreads();
  for (int kk = 2; kk <= NN; kk <<= 1) {
    for (int j = kk >> 1; j > 0; j >>= 1) {
      for (int t = tid; t < NN; t += 1024) {
        int ixj = t ^ j;
        if (ixj > t) {
          bool up = ((t & kk) == 0);
          unsigned long long a = k[t], c = k[ixj];
          if ((a > c) == up) { k[t] = c; k[ixj] = a; }
        }
      }
      __syncthreads();
    }
  }
  for (int j = tid; j < KK; j += 1024) {
    unsigned long long key = ~k[j];
    int i = (NN - 1) - (int)(key & 0xffffffffu);
    perm[b * KK + j] = b * NN + i;
  }
}

// gather kept rows, scale by score, and write new_id (fused)
__global__ void h3_kernel(const float4* __restrict__ h2, const int* __restrict__ perm,
                          const float* __restrict__ score, float4* __restrict__ h3,
                          int* new_id) {
  int idx = blockIdx.x * blockDim.x + threadIdx.x;  // over N1*32 float4s
  if (idx < N1 * 32) {
    int g = idx >> 5, c = idx & 31;
    int p = perm[g];
    if (c == 0) new_id[p] = g;
    float s = score[p];
    float4 v = h2[(size_t)p * 32 + c];
    v.x *= s; v.y *= s; v.z *= s; v.w *= s;
    h3[idx] = v;
  }
}

// ---------------- final: pool-final x3 + MLP + log_softmax ----------------
__global__ void mlp_kernel(const float* __restrict__ pm1, const float* __restrict__ ps1,
                           const float* __restrict__ pm2, const float* __restrict__ ps2,
                           const float* __restrict__ pm3, const float* __restrict__ ps3,
                           const float* __restrict__ Wl1, const float* __restrict__ bl1,
                           const float* __restrict__ Wl2, const float* __restrict__ bl2,
                           const float* __restrict__ Wl3, const float* __restrict__ bl3,
                           float* out) {
  __shared__ float z[256], a1[128], a2[64], a3[10], red[2];
  int b = blockIdx.x, t = threadIdx.x;  // 128 threads
  float m1 = -3.402823466e38f, m2 = m1, m3 = m1;
  float s1 = 0.f, s2 = 0.f, s3 = 0.f;
  for (int s = 0; s < SLICES; ++s) {
    int o = (b * SLICES + s) * 128 + t;
    m1 = fmaxf(m1, pm1[o]); s1 += ps1[o];
    m2 = fmaxf(m2, pm2[o]); s2 += ps2[o];
    m3 = fmaxf(m3, pm3[o]); s3 += ps3[o];
  }
  z[t] = m1 + m2 + m3;
  z[128 + t] = s1 * (1.f / NN) + (s2 + s3) * (1.f / KK);
  __syncthreads();
  {
    float acc = bl1[t];
    for (int q = 0; q < 256; ++q) acc = fmaf(Wl1[t * 256 + q], z[q], acc);
    a1[t] = fmaxf(acc, 0.f);
  }
  __syncthreads();
  if (t < 64) {
    float acc = bl2[t];
    for (int q = 0; q < 128; ++q) acc = fmaf(Wl2[t * 128 + q], a1[q], acc);
    a2[t] = fmaxf(acc, 0.f);
  }
  __syncthreads();
  if (t < 10) {
    float acc = bl3[t];
    for (int q = 0; q < 64; ++q) acc = fmaf(Wl3[t * 64 + q], a2[q], acc);
    a3[t] = acc;
  }
  __syncthreads();
  if (t == 0) {
    float m = a3[0];
    for (int i = 1; i < 10; ++i) m = fmaxf(m, a3[i]);
    float s = 0.f;
    for (int i = 0; i < 10; ++i) s += expf(a3[i] - m);
    red[0] = m;
    red[1] = logf(s);
  }
  __syncthreads();
  if (t < 10) out[b * 10 + t] = a3[t] - red[0] - red[1];
}

extern "C" void kernel_launch(void* const* d_in, const int* in_sizes, int n_in,
                              void* d_out, int out_size, void* d_ws, size_t ws_size,
                              hipStream_t stream) {
  const float* x       = (const float*)d_in[0];
  const int*   src     = (const int*)d_in[1];
  const int*   dst     = (const int*)d_in[2];
  const float* W1_rel  = (const float*)d_in[3];
  const float* b1      = (const float*)d_in[4];
  const float* W1_root = (const float*)d_in[5];
  const float* W2_rel  = (const float*)d_in[6];
  const float* b2      = (const float*)d_in[7];
  const float* W2_root = (const float*)d_in[8];
  const float* W3_rel  = (const float*)d_in[9];
  const float* b3      = (const float*)d_in[10];
  const float* W3_root = (const float*)d_in[11];
  const float* pool_w  = (const float*)d_in[12];
  const float* Wl1     = (const float*)d_in[13];
  const float* bl1     = (const float*)d_in[14];
  const float* Wl2     = (const float*)d_in[15];
  const float* bl2     = (const float*)d_in[16];
  const float* Wl3     = (const float*)d_in[17];
  const float* bl3     = (const float*)d_in[18];
  float* out = (float*)d_out;

  // workspace layout
  char* w = (char*)d_ws;
  size_t off = 0;
  auto alloc = [&](size_t bytes) -> char* {
    off = (off + 255) & ~(size_t)255;
    char* p = w + off;
    off += bytes;
    return p;
  };
  // deg1 | deg2 contiguous (one memset); +4096 ints pad for exscan int4 tiles
  int* degs     = (int*)alloc((NB + N1 + 4096) * 4);
  int* deg1     = degs;
  int* deg2     = degs + NB;
  int* rs1      = (int*)alloc((NB + 1) * 4);
  int* cursor1  = (int*)alloc(NB * 4);
  int* csr1     = (int*)alloc((size_t)EE * 4);
  int* rs2      = (int*)alloc((N1 + 1) * 4);
  int* cursor2  = (int*)alloc(N1 * 4);
  int* csr2     = (int*)alloc((size_t)EE * 4);
  int* new_id   = (int*)alloc(NB * 4);
  int* perm     = (int*)alloc(N1 * 4);
  _Float16* wh1 = (_Float16*)alloc(128 * 128 * 2);
  _Float16* wl1 = (_Float16*)alloc(128 * 128 * 2);
  _Float16* wh2 = (_Float16*)alloc(128 * 256 * 2);
  _Float16* wl2 = (_Float16*)alloc(128 * 256 * 2);
  _Float16* wh3 = (_Float16*)alloc(128 * 256 * 2);
  _Float16* wl3 = (_Float16*)alloc(128 * 256 * 2);
  float* bufA   = (float*)alloc((size_t)NB * HH * 4);  // h1, then h3
  float* bufB   = (float*)alloc((size_t)NB * HH * 4);  // h2, then h4
  float* score  = (float*)alloc(NB * 4);
  float* pm1    = (float*)alloc(BG * SLICES * HH * 4);
  float* ps1    = (float*)alloc(BG * SLICES * HH * 4);
  float* pm2    = (float*)alloc(BG * SLICES * HH * 4);
  float* ps2    = (float*)alloc(BG * SLICES * HH * 4);
  float* pm3    = (float*)alloc(BG * SLICES * HH * 4);
  float* ps3    = (float*)alloc(BG * SLICES * HH * 4);
  if (off > ws_size) return;  // workspace too small: fail visibly

  const int TB = 256;
  const int egrid = (EE + TB - 1) / TB;

  hipMemsetAsync(degs, 0, (NB + N1 + 4096) * 4, stream);
  hipMemsetAsync(new_id, 0xFF, NB * 4, stream);  // -1

  prep_weights_f16<<<(128 * 128 + 2 * 128 * 256 + TB - 1) / TB, TB, 0, stream>>>(
      W1_rel, W1_root, W2_rel, W2_root, W3_rel, W3_root, wh1, wl1, wh2, wl2, wh3, wl3);

  // CSR1 (src -> dst)
  deg_kernel<<<egrid, TB, 0, stream>>>(dst, deg1, EE);
  exscan_kernel<<<1, 1024, 0, stream>>>(deg1, rs1, cursor1, NB);
  scatter_kernel<<<egrid, TB, 0, stream>>>(src, dst, cursor1, csr1, EE);

  // conv1 (K = 64 agg + 64 root), gather fused
  conv_mfma<64, 64><<<NB / 64, 512, 0, stream>>>(x, x, rs1, csr1, wh1, wl1, b1, bufA, NB,
                                                 NB / 64);
  pool_partial_kernel<<<BG * SLICES, 128, 0, stream>>>(bufA, NN, pm1, ps1);

  // conv2, gather fused
  conv_mfma<128, 128><<<NB / 64, 512, 0, stream>>>(bufA, bufA, rs1, csr1, wh2, wl2, b2, bufB,
                                                   NB, NB / 64);

  // topk
  score_kernel<<<NB / 4, 256, 0, stream>>>(bufB, pool_w, score, NB);
  topk_kernel<<<BG, 1024, 0, stream>>>(score, perm);
  h3_kernel<<<(N1 * 32 + TB - 1) / TB, TB, 0, stream>>>((const float4*)bufB, perm, score,
                                                        (float4*)bufA, new_id);
  pool_partial_kernel<<<BG * SLICES, 128, 0, stream>>>(bufA, KK, pm2, ps2);

  // CSR2 over remapped kept edges
  deg2_kernel<<<egrid, TB, 0, stream>>>(src, dst, new_id, deg2, EE);
  exscan_kernel<<<1, 1024, 0, stream>>>(deg2, rs2, cursor2, N1);
  scatter2_kernel<<<egrid, TB, 0, stream>>>(src, dst, new_id, cursor2, csr2, EE);

  // conv3, gather fused
  conv_mfma<128, 128><<<(N1 + 63) / 64, 512, 0, stream>>>(bufA, bufA, rs2, csr2, wh3, wl3,
                                                          b3, bufB, N1, (N1 + 63) / 64);
  pool_partial_kernel<<<BG * SLICES, 128, 0, stream>>>(bufB, KK, pm3, ps3);

  // pool finals + MLP head + log_softmax (fused)
  mlp_kernel<<<BG, 128, 0, stream>>>(pm1, ps1, pm2, ps2, pm3, ps3,
                                     Wl1, bl1, Wl2, bl2, Wl3, bl3, out);
}

// Round 9
// 316.290 us; speedup vs baseline: 1.1537x; 1.1537x over previous
//
#include <hip/hip_runtime.h>
#include <hip/hip_bf16.h>
#include <math.h>

#define NB 32768      // total nodes (B*N)
#define NN 2048       // nodes per graph
#define BG 16         // graphs
#define KK 1639       // kept per graph
#define N1 (BG*KK)    // 26224 kept nodes total
#define EE 524288     // total edges
#define HH 128        // hidden
#define FIN 64        // input features
#define SLICES 16

using half8 = __attribute__((ext_vector_type(8))) _Float16;
using f32x4 = __attribute__((ext_vector_type(4))) float;

// ---------------- CSR build ----------------
__global__ void deg_kernel(const int* __restrict__ dst, int* deg, int n) {
  int e = blockIdx.x * blockDim.x + threadIdx.x;
  if (e < n) atomicAdd(&deg[dst[e]], 1);
}

__global__ void deg2_kernel(const int* __restrict__ src, const int* __restrict__ dst,
                            const int* __restrict__ new_id, int* deg, int n) {
  int e = blockIdx.x * blockDim.x + threadIdx.x;
  if (e < n) {
    int a = new_id[src[e]], d = new_id[dst[e]];
    if (a >= 0 && d >= 0) atomicAdd(&deg[d], 1);
  }
}

// single-block coalesced exclusive scan over tiles of 4096 (int4/lane);
// writes rs[0..n] and cursor[0..n-1]. Caller must pad deg so int4 reads up to
// ceil(n/4096)*4096 stay in-bounds.
__global__ void exscan_kernel(const int* __restrict__ deg, int* rs, int* cursor, int n) {
  __shared__ int wsum[16];
  __shared__ int carry;
  int t = threadIdx.x;  // 1024
  int lane = t & 63, wid = t >> 6;
  if (t == 0) carry = 0;
  __syncthreads();
  int ntiles = (n + 4095) >> 12;
  for (int tile = 0; tile < ntiles; ++tile) {
    int idx = (tile << 12) + t * 4;
    int4 v4 = *(const int4*)(deg + idx);  // coalesced 16B/lane (padded alloc)
    int v0 = (idx + 0 < n) ? v4.x : 0;
    int v1 = (idx + 1 < n) ? v4.y : 0;
    int v2 = (idx + 2 < n) ? v4.z : 0;
    int v3 = (idx + 3 < n) ? v4.w : 0;
    int s = v0 + v1 + v2 + v3;
    int pre = s;
#pragma unroll
    for (int off = 1; off < 64; off <<= 1) {
      int u = __shfl_up(pre, off, 64);
      if (lane >= off) pre += u;
    }
    if (lane == 63) wsum[wid] = pre;
    __syncthreads();
    int wbase = 0;
#pragma unroll
    for (int ww = 0; ww < 16; ++ww)
      if (ww < wid) wbase += wsum[ww];
    int ex = carry + wbase + (pre - s);
    int4 e4 = make_int4(ex, ex + v0, ex + v0 + v1, ex + v0 + v1 + v2);
    if (idx + 3 < n) {
      *(int4*)(rs + idx) = e4;
      *(int4*)(cursor + idx) = e4;
    } else {
      if (idx + 0 < n) { rs[idx + 0] = e4.x; cursor[idx + 0] = e4.x; }
      if (idx + 1 < n) { rs[idx + 1] = e4.y; cursor[idx + 1] = e4.y; }
      if (idx + 2 < n) { rs[idx + 2] = e4.z; cursor[idx + 2] = e4.z; }
    }
    int tot = 0;
    if (t == 1023) tot = ex + s;
    __syncthreads();            // all carry-reads done before update
    if (t == 1023) carry = tot;
    __syncthreads();
  }
  if (t == 0) rs[n] = carry;
}

__global__ void scatter_kernel(const int* __restrict__ src, const int* __restrict__ dst,
                               int* cursor, int* csr, int n) {
  int e = blockIdx.x * blockDim.x + threadIdx.x;
  if (e < n) {
    int d = dst[e];
    int p = atomicAdd(&cursor[d], 1);
    csr[p] = src[e];
  }
}

__global__ void scatter2_kernel(const int* __restrict__ src, const int* __restrict__ dst,
                                const int* __restrict__ new_id, int* cursor, int* csr, int n) {
  int e = blockIdx.x * blockDim.x + threadIdx.x;
  if (e < n) {
    int a = new_id[src[e]], d = new_id[dst[e]];
    if (a >= 0 && d >= 0) {
      int p = atomicAdd(&cursor[d], 1);
      csr[p] = a;
    }
  }
}

// ---------------- fused agg + conv GEMM via f16 split-precision MFMA ----------------
// out = relu([agg|x] @ Wcat^T + b), agg gathered in-kernel from CSR.
// Block: 512 thr = 8 waves; tile = 64 rows x 128 cols; wave = 64x16 (4 row-frags).
// Phase order tuned for VGPR/MLP: (1) CSR gather FIRST (8 thr/row, edge loop
// unrolled x4 with batched index loads -> 8-16 feature loads in flight/lane),
// (2) root staging + W preload (reg-stationary), (3) barrier, (4) pure
// ds_read+MFMA k-loop (3-product split-precision, err ~2^-22).
// POOL=1: emit per-block column max/sum partials (x1 pool fused; needs 64 | rows/graph).
template <int KD1, int KD2, int POOL>
__global__ __launch_bounds__(512, 4) void conv_mfma(
    const float* __restrict__ feat, const float* __restrict__ xr,
    const int* __restrict__ rs, const int* __restrict__ csr,
    const _Float16* __restrict__ Wh, const _Float16* __restrict__ Wl,
    const float* __restrict__ bias, float* __restrict__ out, int M, int nwg,
    float* __restrict__ pmax, float* __restrict__ psum) {
  constexpr int KTOT = KD1 + KD2;
  constexpr int NSTEP = KTOT / 32;
  constexpr int CPT = KD1 / 32;   // float4 chunks per gather thread (2 or 4)
  __shared__ _Float16 ah_lds[64 * KTOT];
  __shared__ _Float16 al_lds[64 * KTOT];

  int tid = threadIdx.x;
  int lane = tid & 63, wid = tid >> 6;
  // bijective XCD-chunk swizzle (m204)
  int bq = nwg >> 3, br = nwg & 7, bx = blockIdx.x & 7, bi = blockIdx.x >> 3;
  int swz = (bx < br ? bx * (bq + 1) : br * (bq + 1) + (bx - br) * bq) + bi;
  int row0 = swz * 64;
  int ch0 = wid * 16;           // 8 waves cover the 128 output cols
  int col = lane & 15;
  int kseg = (lane >> 4) * 8;

  // ---- Phase 1a: CSR gather (k in [0, KD1)); 8 threads/row, all 512 active ----
  {
    int gr = tid >> 3;          // row within tile (0..63)
    int gj = tid & 7;           // chunk group
    int grow = row0 + gr;
    if (grow >= M) grow = M - 1;  // clamp (dup work, stores guarded)
    const float4* fbase = (const float4*)feat + gj * CPT;
    int e0 = rs[grow], e1 = rs[grow + 1];
    f32x4 s[CPT];
#pragma unroll
    for (int j = 0; j < CPT; ++j) s[j] = (f32x4){0.f, 0.f, 0.f, 0.f};
    int e = e0;
    for (; e + 3 < e1; e += 4) {   // x4 edge unroll: up to 4*CPT loads in flight
      int c0 = csr[e], c1 = csr[e + 1], c2 = csr[e + 2], c3 = csr[e + 3];
      const float4* p0 = fbase + (size_t)c0 * (KD1 / 4);
      const float4* p1 = fbase + (size_t)c1 * (KD1 / 4);
      const float4* p2 = fbase + (size_t)c2 * (KD1 / 4);
      const float4* p3 = fbase + (size_t)c3 * (KD1 / 4);
      float4 v0[CPT], v1[CPT], v2[CPT], v3[CPT];
#pragma unroll
      for (int j = 0; j < CPT; ++j) { v0[j] = p0[j]; v1[j] = p1[j]; v2[j] = p2[j]; v3[j] = p3[j]; }
#pragma unroll
      for (int j = 0; j < CPT; ++j) {
        s[j] += (f32x4){v0[j].x, v0[j].y, v0[j].z, v0[j].w};
        s[j] += (f32x4){v1[j].x, v1[j].y, v1[j].z, v1[j].w};
        s[j] += (f32x4){v2[j].x, v2[j].y, v2[j].z, v2[j].w};
        s[j] += (f32x4){v3[j].x, v3[j].y, v3[j].z, v3[j].w};
      }
    }
    for (; e < e1; ++e) {
      const float4* p = fbase + (size_t)csr[e] * (KD1 / 4);
#pragma unroll
      for (int j = 0; j < CPT; ++j) {
        float4 v = p[j];
        s[j] += (f32x4){v.x, v.y, v.z, v.w};
      }
    }
    // convert to f16 hi/lo and store (16B granules, XOR-swizzled)
    int base = (gr * KTOT + gj * CPT * 4) * 2;
    int sw = (gr & 7) << 4;
#pragma unroll
    for (int h = 0; h < CPT / 2; ++h) {
      half8 vh, vl;
#pragma unroll
      for (int j = 0; j < 8; ++j) {
        float f = s[h * 2 + (j >> 2)][j & 3];
        _Float16 hi = (_Float16)f;
        vh[j] = hi;
        vl[j] = (_Float16)(f - (float)hi);
      }
      int byte = (base + h * 16) ^ sw;
      *(half8*)((char*)ah_lds + byte) = vh;
      *(half8*)((char*)al_lds + byte) = vl;
    }
  }

  // ---- Phase 1b: root staging (k in [KD1, KTOT)) ----
  for (int idx = tid; idx < 64 * KD2 / 8; idx += 512) {
    int row = idx / (KD2 / 8);
    int kc = (idx % (KD2 / 8)) * 8;
    int grow = row0 + row;
    if (grow >= M) grow = M - 1;
    const float* sp = xr + (size_t)grow * KD2 + kc;
    float4 a0 = *(const float4*)sp;
    float4 a1 = *(const float4*)(sp + 4);
    float av[8] = {a0.x, a0.y, a0.z, a0.w, a1.x, a1.y, a1.z, a1.w};
    half8 vh, vl;
#pragma unroll
    for (int j = 0; j < 8; ++j) {
      _Float16 h = (_Float16)av[j];
      vh[j] = h;
      vl[j] = (_Float16)(av[j] - (float)h);
    }
    int byte = ((row * KTOT + KD1 + kc) * 2) ^ ((row & 7) << 4);
    *(half8*)((char*)ah_lds + byte) = vh;
    *(half8*)((char*)al_lds + byte) = vl;
  }

  // ---- W preload AFTER gather (keeps gather VGPR pressure low) ----
  half8 wh_r[NSTEP], wl_r[NSTEP];
#pragma unroll
  for (int s = 0; s < NSTEP; ++s) {
    size_t wof = (size_t)(ch0 + col) * KTOT + s * 32 + kseg;
    wh_r[s] = *(const half8*)(Wh + wof);
    wl_r[s] = *(const half8*)(Wl + wof);
  }
  __syncthreads();

  // ---- Phase 2: k-loop, pure ds_read + MFMA ----
  f32x4 acc[4];
#pragma unroll
  for (int rf = 0; rf < 4; ++rf) acc[rf] = (f32x4){0.f, 0.f, 0.f, 0.f};
  int r = lane & 15;
#pragma unroll
  for (int s = 0; s < NSTEP; ++s) {
#pragma unroll
    for (int rf = 0; rf < 4; ++rf) {
      int row = rf * 16 + r;
      int byte = ((row * KTOT + s * 32 + kseg) * 2) ^ ((row & 7) << 4);
      half8 a_h = *(const half8*)((const char*)ah_lds + byte);
      half8 a_l = *(const half8*)((const char*)al_lds + byte);
      acc[rf] = __builtin_amdgcn_mfma_f32_16x16x32_f16(a_l, wh_r[s], acc[rf], 0, 0, 0);
      acc[rf] = __builtin_amdgcn_mfma_f32_16x16x32_f16(a_h, wl_r[s], acc[rf], 0, 0, 0);
      acc[rf] = __builtin_amdgcn_mfma_f32_16x16x32_f16(a_h, wh_r[s], acc[rf], 0, 0, 0);
    }
  }

  // ---- epilogue: bias + relu (+ optional fused column pool partials) ----
  float bv = bias[ch0 + col];
  float cmax = -3.402823466e38f, csum = 0.f;
#pragma unroll
  for (int rf = 0; rf < 4; ++rf) {
    int orow0 = row0 + rf * 16 + (lane >> 4) * 4;
#pragma unroll
    for (int rr = 0; rr < 4; ++rr) {
      int orow = orow0 + rr;
      float v = fmaxf(acc[rf][rr] + bv, 0.f);
      if (orow < M) out[(size_t)orow * HH + ch0 + col] = v;
      if (POOL) { cmax = fmaxf(cmax, v); csum += v; }
    }
  }
  if (POOL) {
    // combine the 4 row-groups (lanes 16 apart share a column)
    cmax = fmaxf(cmax, __shfl_xor(cmax, 16, 64)); csum += __shfl_xor(csum, 16, 64);
    cmax = fmaxf(cmax, __shfl_xor(cmax, 32, 64)); csum += __shfl_xor(csum, 32, 64);
    if ((lane >> 4) == 0) {
      int g = row0 >> 11;           // graph (rows/graph = 2048)
      int sb = (row0 & 2047) >> 6;  // slice 0..31
      pmax[(g * 32 + sb) * HH + ch0 + col] = cmax;
      psum[(g * 32 + sb) * HH + ch0 + col] = csum;
    }
  }
}

// ---------------- weight prep: split Wcat[o][k] into f16 hi + lo planes ----------------
__global__ void prep_weights_f16(const float* __restrict__ W1_rel, const float* __restrict__ W1_root,
                                 const float* __restrict__ W2_rel, const float* __restrict__ W2_root,
                                 const float* __restrict__ W3_rel, const float* __restrict__ W3_root,
                                 _Float16* wh1, _Float16* wl1, _Float16* wh2, _Float16* wl2,
                                 _Float16* wh3, _Float16* wl3) {
  int idx = blockIdx.x * blockDim.x + threadIdx.x;
  float v;
  _Float16* ph;
  _Float16* pl;
  int j;
  if (idx < 128 * 128) {
    j = idx;
    int o = j >> 7, k = j & 127;
    v = (k < 64) ? W1_rel[o * 64 + k] : W1_root[o * 64 + (k - 64)];
    ph = wh1; pl = wl1;
  } else if (idx < 128 * 128 + 128 * 256) {
    j = idx - 128 * 128;
    int o = j >> 8, k = j & 255;
    v = (k < 128) ? W2_rel[o * 128 + k] : W2_root[o * 128 + (k - 128)];
    ph = wh2; pl = wl2;
  } else if (idx < 128 * 128 + 2 * 128 * 256) {
    j = idx - 128 * 128 - 128 * 256;
    int o = j >> 8, k = j & 255;
    v = (k < 128) ? W3_rel[o * 128 + k] : W3_root[o * 128 + (k - 128)];
    ph = wh3; pl = wl3;
  } else {
    return;
  }
  _Float16 h = (_Float16)v;
  ph[j] = h;
  pl[j] = (_Float16)(v - (float)h);
}

// ---------------- pooling partials (x2, x3) ----------------
__global__ void pool_partial_kernel(const float* __restrict__ h, int rows_per_graph,
                                    float* pmax, float* psum) {
  int b = blockIdx.x / SLICES, s = blockIdx.x % SLICES;
  int f = threadIdx.x;
  int per = (rows_per_graph + SLICES - 1) / SLICES;
  int r0 = s * per, r1 = min(rows_per_graph, r0 + per);
  float m = -3.402823466e38f, sum = 0.f;
  for (int r = r0; r < r1; ++r) {
    float v = h[(size_t)(b * rows_per_graph + r) * HH + f];
    m = fmaxf(m, v);
    sum += v;
  }
  pmax[(b * SLICES + s) * HH + f] = m;
  psum[(b * SLICES + s) * HH + f] = sum;
}

// ---------------- scoring (norm fused per-wave) ----------------
__global__ void score_kernel(const float* __restrict__ h2, const float* __restrict__ w,
                             float* score, int M) {
  int wave = threadIdx.x >> 6;
  int lane = threadIdx.x & 63;
  int i = blockIdx.x * (blockDim.x >> 6) + wave;
  if (i >= M) return;
  float wl0 = w[lane], wl1 = w[64 + lane];
  float acc = h2[i * HH + lane] * wl0 + h2[i * HH + 64 + lane] * wl1;
  float nsq = wl0 * wl0 + wl1 * wl1;
  for (int off = 32; off > 0; off >>= 1) {
    acc += __shfl_down(acc, off, 64);
    nsq += __shfl_down(nsq, off, 64);
  }
  if (lane == 0) score[i] = tanhf(acc / sqrtf(nsq));
}

// per-graph bitonic sort of 2048 (score,index) keys; keep top K, tie-break lowest index
__global__ void topk_kernel(const float* __restrict__ score, int* perm) {
  __shared__ unsigned long long k[NN];
  int b = blockIdx.x;
  int tid = threadIdx.x;  // 1024
  for (int i = tid; i < NN; i += 1024) {
    float s = score[b * NN + i];
    unsigned u = __float_as_uint(s);
    u = (u & 0x80000000u) ? ~u : (u | 0x80000000u);
    unsigned long long key = ((unsigned long long)u << 32) | (unsigned)(NN - 1 - i);
    k[i] = ~key;  // ascending sort of ~key == descending by (score, -index)
  }
  __syncthreads();
  for (int kk = 2; kk <= NN; kk <<= 1) {
    for (int j = kk >> 1; j > 0; j >>= 1) {
      for (int t = tid; t < NN; t += 1024) {
        int ixj = t ^ j;
        if (ixj > t) {
          bool up = ((t & kk) == 0);
          unsigned long long a = k[t], c = k[ixj];
          if ((a > c) == up) { k[t] = c; k[ixj] = a; }
        }
      }
      __syncthreads();
    }
  }
  for (int j = tid; j < KK; j += 1024) {
    unsigned long long key = ~k[j];
    int i = (NN - 1) - (int)(key & 0xffffffffu);
    perm[b * KK + j] = b * NN + i;
  }
}

// gather kept rows, scale by score, and write new_id (fused)
__global__ void h3_kernel(const float4* __restrict__ h2, const int* __restrict__ perm,
                          const float* __restrict__ score, float4* __restrict__ h3,
                          int* new_id) {
  int idx = blockIdx.x * blockDim.x + threadIdx.x;  // over N1*32 float4s
  if (idx < N1 * 32) {
    int g = idx >> 5, c = idx & 31;
    int p = perm[g];
    if (c == 0) new_id[p] = g;
    float s = score[p];
    float4 v = h2[(size_t)p * 32 + c];
    v.x *= s; v.y *= s; v.z *= s; v.w *= s;
    h3[idx] = v;
  }
}

// ---------------- final: pool-final x3 + MLP + log_softmax ----------------
__global__ void mlp_kernel(const float* __restrict__ pm1, const float* __restrict__ ps1,
                           const float* __restrict__ pm2, const float* __restrict__ ps2,
                           const float* __restrict__ pm3, const float* __restrict__ ps3,
                           const float* __restrict__ Wl1, const float* __restrict__ bl1,
                           const float* __restrict__ Wl2, const float* __restrict__ bl2,
                           const float* __restrict__ Wl3, const float* __restrict__ bl3,
                           float* out) {
  __shared__ float z[256], a1[128], a2[64], a3[10], red[2];
  int b = blockIdx.x, t = threadIdx.x;  // 128 threads
  float m1 = -3.402823466e38f, m2 = m1, m3 = m1;
  float s1 = 0.f, s2 = 0.f, s3 = 0.f;
  for (int s = 0; s < 32; ++s) {       // x1 partials: 32 slices (from conv1 blocks)
    int o = (b * 32 + s) * 128 + t;
    m1 = fmaxf(m1, pm1[o]); s1 += ps1[o];
  }
  for (int s = 0; s < SLICES; ++s) {   // x2/x3 partials: 16 slices
    int o = (b * SLICES + s) * 128 + t;
    m2 = fmaxf(m2, pm2[o]); s2 += ps2[o];
    m3 = fmaxf(m3, pm3[o]); s3 += ps3[o];
  }
  z[t] = m1 + m2 + m3;
  z[128 + t] = s1 * (1.f / NN) + (s2 + s3) * (1.f / KK);
  __syncthreads();
  {
    float acc = bl1[t];
    for (int q = 0; q < 256; ++q) acc = fmaf(Wl1[t * 256 + q], z[q], acc);
    a1[t] = fmaxf(acc, 0.f);
  }
  __syncthreads();
  if (t < 64) {
    float acc = bl2[t];
    for (int q = 0; q < 128; ++q) acc = fmaf(Wl2[t * 128 + q], a1[q], acc);
    a2[t] = fmaxf(acc, 0.f);
  }
  __syncthreads();
  if (t < 10) {
    float acc = bl3[t];
    for (int q = 0; q < 64; ++q) acc = fmaf(Wl3[t * 64 + q], a2[q], acc);
    a3[t] = acc;
  }
  __syncthreads();
  if (t == 0) {
    float m = a3[0];
    for (int i = 1; i < 10; ++i) m = fmaxf(m, a3[i]);
    float s = 0.f;
    for (int i = 0; i < 10; ++i) s += expf(a3[i] - m);
    red[0] = m;
    red[1] = logf(s);
  }
  __syncthreads();
  if (t < 10) out[b * 10 + t] = a3[t] - red[0] - red[1];
}

extern "C" void kernel_launch(void* const* d_in, const int* in_sizes, int n_in,
                              void* d_out, int out_size, void* d_ws, size_t ws_size,
                              hipStream_t stream) {
  const float* x       = (const float*)d_in[0];
  const int*   src     = (const int*)d_in[1];
  const int*   dst     = (const int*)d_in[2];
  const float* W1_rel  = (const float*)d_in[3];
  const float* b1      = (const float*)d_in[4];
  const float* W1_root = (const float*)d_in[5];
  const float* W2_rel  = (const float*)d_in[6];
  const float* b2      = (const float*)d_in[7];
  const float* W2_root = (const float*)d_in[8];
  const float* W3_rel  = (const float*)d_in[9];
  const float* b3      = (const float*)d_in[10];
  const float* W3_root = (const float*)d_in[11];
  const float* pool_w  = (const float*)d_in[12];
  const float* Wl1     = (const float*)d_in[13];
  const float* bl1     = (const float*)d_in[14];
  const float* Wl2     = (const float*)d_in[15];
  const float* bl2     = (const float*)d_in[16];
  const float* Wl3     = (const float*)d_in[17];
  const float* bl3     = (const float*)d_in[18];
  float* out = (float*)d_out;

  // workspace layout
  char* w = (char*)d_ws;
  size_t off = 0;
  auto alloc = [&](size_t bytes) -> char* {
    off = (off + 255) & ~(size_t)255;
    char* p = w + off;
    off += bytes;
    return p;
  };
  // deg1 | deg2 contiguous (one memset); +4096 ints pad for exscan int4 tiles
  int* degs     = (int*)alloc((NB + N1 + 4096) * 4);
  int* deg1     = degs;
  int* deg2     = degs + NB;
  int* rs1      = (int*)alloc((NB + 1) * 4);
  int* cursor1  = (int*)alloc(NB * 4);
  int* csr1     = (int*)alloc((size_t)EE * 4);
  int* rs2      = (int*)alloc((N1 + 1) * 4);
  int* cursor2  = (int*)alloc(N1 * 4);
  int* deg2pad  = deg2;  // (unused alias)
  int* csr2     = (int*)alloc((size_t)EE * 4);
  int* new_id   = (int*)alloc(NB * 4);
  int* perm     = (int*)alloc(N1 * 4);
  _Float16* wh1 = (_Float16*)alloc(128 * 128 * 2);
  _Float16* wl1 = (_Float16*)alloc(128 * 128 * 2);
  _Float16* wh2 = (_Float16*)alloc(128 * 256 * 2);
  _Float16* wl2 = (_Float16*)alloc(128 * 256 * 2);
  _Float16* wh3 = (_Float16*)alloc(128 * 256 * 2);
  _Float16* wl3 = (_Float16*)alloc(128 * 256 * 2);
  float* bufA   = (float*)alloc((size_t)NB * HH * 4);  // h1, then h3
  float* bufB   = (float*)alloc((size_t)NB * HH * 4);  // h2, then h4
  float* score  = (float*)alloc(NB * 4);
  float* pm1    = (float*)alloc(BG * 32 * HH * 4);     // 32 slices (fused conv1 pool)
  float* ps1    = (float*)alloc(BG * 32 * HH * 4);
  float* pm2    = (float*)alloc(BG * SLICES * HH * 4);
  float* ps2    = (float*)alloc(BG * SLICES * HH * 4);
  float* pm3    = (float*)alloc(BG * SLICES * HH * 4);
  float* ps3    = (float*)alloc(BG * SLICES * HH * 4);
  if (off > ws_size) return;  // workspace too small: fail visibly
  (void)deg2pad;

  const int TB = 256;
  const int egrid = (EE + TB - 1) / TB;

  hipMemsetAsync(degs, 0, (NB + N1 + 4096) * 4, stream);
  hipMemsetAsync(new_id, 0xFF, NB * 4, stream);  // -1

  prep_weights_f16<<<(128 * 128 + 2 * 128 * 256 + TB - 1) / TB, TB, 0, stream>>>(
      W1_rel, W1_root, W2_rel, W2_root, W3_rel, W3_root, wh1, wl1, wh2, wl2, wh3, wl3);

  // CSR1 (src -> dst)
  deg_kernel<<<egrid, TB, 0, stream>>>(dst, deg1, EE);
  exscan_kernel<<<1, 1024, 0, stream>>>(deg1, rs1, cursor1, NB);
  scatter_kernel<<<egrid, TB, 0, stream>>>(src, dst, cursor1, csr1, EE);

  // conv1 (K = 64 agg + 64 root), gather + x1 pool fused
  conv_mfma<64, 64, 1><<<NB / 64, 512, 0, stream>>>(x, x, rs1, csr1, wh1, wl1, b1, bufA, NB,
                                                    NB / 64, pm1, ps1);

  // conv2, gather fused
  conv_mfma<128, 128, 0><<<NB / 64, 512, 0, stream>>>(bufA, bufA, rs1, csr1, wh2, wl2, b2,
                                                      bufB, NB, NB / 64, nullptr, nullptr);

  // topk
  score_kernel<<<NB / 4, 256, 0, stream>>>(bufB, pool_w, score, NB);
  topk_kernel<<<BG, 1024, 0, stream>>>(score, perm);
  h3_kernel<<<(N1 * 32 + TB - 1) / TB, TB, 0, stream>>>((const float4*)bufB, perm, score,
                                                        (float4*)bufA, new_id);
  pool_partial_kernel<<<BG * SLICES, 128, 0, stream>>>(bufA, KK, pm2, ps2);

  // CSR2 over remapped kept edges
  deg2_kernel<<<egrid, TB, 0, stream>>>(src, dst, new_id, deg2, EE);
  exscan_kernel<<<1, 1024, 0, stream>>>(deg2, rs2, cursor2, N1);
  scatter2_kernel<<<egrid, TB, 0, stream>>>(src, dst, new_id, cursor2, csr2, EE);

  // conv3, gather fused
  conv_mfma<128, 128, 0><<<(N1 + 63) / 64, 512, 0, stream>>>(bufA, bufA, rs2, csr2, wh3, wl3,
                                                             b3, bufB, N1, (N1 + 63) / 64,
                                                             nullptr, nullptr);
  pool_partial_kernel<<<BG * SLICES, 128, 0, stream>>>(bufB, KK, pm3, ps3);

  // pool finals + MLP head + log_softmax (fused)
  mlp_kernel<<<BG, 128, 0, stream>>>(pm1, ps1, pm2, ps2, pm3, ps3,
                                     Wl1, bl1, Wl2, bl2, Wl3, bl3, out);
}

// Round 10
// 291.574 us; speedup vs baseline: 1.2515x; 1.0848x over previous
//
#include <hip/hip_runtime.h>
#include <hip/hip_bf16.h>
#include <math.h>

#define NB 32768      // total nodes (B*N)
#define NN 2048       // nodes per graph
#define BG 16         // graphs
#define KK 1639       // kept per graph (0.8*2048 ceil)
#define KKP 1664      // kept rows padded to 64*26 = 13*128
#define N1 (BG*KK)    // 26224 real kept nodes
#define N1P (BG*KKP)  // 26624 padded kept rows
#define EE 524288     // total edges
#define HH 128        // hidden
#define FIN 64        // input features

using half8 = __attribute__((ext_vector_type(8))) _Float16;
using f32x4 = __attribute__((ext_vector_type(4))) float;

// ---------------- CSR build ----------------
__global__ void deg_kernel(const int* __restrict__ dst, int* deg, int n) {
  int e = blockIdx.x * blockDim.x + threadIdx.x;
  if (e < n) atomicAdd(&deg[dst[e]], 1);
}

__global__ void deg2_kernel(const int* __restrict__ src, const int* __restrict__ dst,
                            const int* __restrict__ new_id, int* deg, int n) {
  int e = blockIdx.x * blockDim.x + threadIdx.x;
  if (e < n) {
    int a = new_id[src[e]], d = new_id[dst[e]];
    if (a >= 0 && d >= 0) atomicAdd(&deg[d], 1);
  }
}

// single-block coalesced exclusive scan (int4 tiles of 4096); deg must be padded.
__global__ void exscan_kernel(const int* __restrict__ deg, int* rs, int* cursor, int n) {
  __shared__ int wsum[16];
  __shared__ int carry;
  int t = threadIdx.x;  // 1024
  int lane = t & 63, wid = t >> 6;
  if (t == 0) carry = 0;
  __syncthreads();
  int ntiles = (n + 4095) >> 12;
  for (int tile = 0; tile < ntiles; ++tile) {
    int idx = (tile << 12) + t * 4;
    int4 v4 = *(const int4*)(deg + idx);
    int v0 = (idx + 0 < n) ? v4.x : 0;
    int v1 = (idx + 1 < n) ? v4.y : 0;
    int v2 = (idx + 2 < n) ? v4.z : 0;
    int v3 = (idx + 3 < n) ? v4.w : 0;
    int s = v0 + v1 + v2 + v3;
    int pre = s;
#pragma unroll
    for (int off = 1; off < 64; off <<= 1) {
      int u = __shfl_up(pre, off, 64);
      if (lane >= off) pre += u;
    }
    if (lane == 63) wsum[wid] = pre;
    __syncthreads();
    int wbase = 0;
#pragma unroll
    for (int ww = 0; ww < 16; ++ww)
      if (ww < wid) wbase += wsum[ww];
    int ex = carry + wbase + (pre - s);
    int4 e4 = make_int4(ex, ex + v0, ex + v0 + v1, ex + v0 + v1 + v2);
    if (idx + 3 < n) {
      *(int4*)(rs + idx) = e4;
      *(int4*)(cursor + idx) = e4;
    } else {
      if (idx + 0 < n) { rs[idx + 0] = e4.x; cursor[idx + 0] = e4.x; }
      if (idx + 1 < n) { rs[idx + 1] = e4.y; cursor[idx + 1] = e4.y; }
      if (idx + 2 < n) { rs[idx + 2] = e4.z; cursor[idx + 2] = e4.z; }
    }
    int tot = 0;
    if (t == 1023) tot = ex + s;
    __syncthreads();
    if (t == 1023) carry = tot;
    __syncthreads();
  }
  if (t == 0) rs[n] = carry;
}

__global__ void scatter_kernel(const int* __restrict__ src, const int* __restrict__ dst,
                               int* cursor, int* csr, int n) {
  int e = blockIdx.x * blockDim.x + threadIdx.x;
  if (e < n) {
    int d = dst[e];
    int p = atomicAdd(&cursor[d], 1);
    csr[p] = src[e];
  }
}

__global__ void scatter2_kernel(const int* __restrict__ src, const int* __restrict__ dst,
                                const int* __restrict__ new_id, int* cursor, int* csr, int n) {
  int e = blockIdx.x * blockDim.x + threadIdx.x;
  if (e < n) {
    int a = new_id[src[e]], d = new_id[dst[e]];
    if (a >= 0 && d >= 0) {
      int p = atomicAdd(&cursor[d], 1);
      csr[p] = a;
    }
  }
}

// ---------------- fused agg + conv GEMM (+optional pool / score epilogues) ----------------
// out = relu([agg|x] @ Wcat^T + b); agg gathered in-kernel from CSR.
// 512 thr = 8 waves; tile = 64 rows x 128 cols; wave = 64x16 (4 row frags).
// Phase 1: CSR gather (8 thr/row, x4 edge unroll) + root staging -> f16 hi/lo
//   XOR-swizzled LDS planes. Phase 2: k-loop = ds_read + MFMA with W double-
//   buffered from L2 (16 VGPR window, no stationary 64-VGPR set).
// POOL=1: x1-pool partials (2048 rows/graph, 32 slices). POOL=2: x3-pool
//   partials (1664 rows/graph padded, 26 slices, rows >=1639 masked).
// SCORE=1: per-row tanh(dot(h,w)/||w||) via shfl col-reduce + LDS cross-wave.
template <int KD1, int KD2, int POOL, int SCORE>
__global__ __launch_bounds__(512, 4) void conv_mfma(
    const float* __restrict__ feat, const float* __restrict__ xr,
    const int* __restrict__ rs, const int* __restrict__ csr,
    const _Float16* __restrict__ Wh, const _Float16* __restrict__ Wl,
    const float* __restrict__ bias, float* __restrict__ out, int M, int nwg,
    float* __restrict__ pmax, float* __restrict__ psum,
    const float* __restrict__ pw, float* __restrict__ score) {
  constexpr int KTOT = KD1 + KD2;
  constexpr int NSTEP = KTOT / 32;
  constexpr int CPT = KD1 / 32;   // float4 chunks per gather thread
  __shared__ _Float16 ah_lds[64 * KTOT];
  __shared__ _Float16 al_lds[64 * KTOT];
  __shared__ float sdot[64][8];
  __shared__ float swsq[8];

  int tid = threadIdx.x;
  int lane = tid & 63, wid = tid >> 6;
  // bijective XCD-chunk swizzle (m204)
  int bq = nwg >> 3, br = nwg & 7, bx = blockIdx.x & 7, bi = blockIdx.x >> 3;
  int swz = (bx < br ? bx * (bq + 1) : br * (bq + 1) + (bx - br) * bq) + bi;
  int row0 = swz * 64;
  int ch0 = wid * 16;
  int col = lane & 15;
  int kseg = (lane >> 4) * 8;

  // ---- Phase 1a: CSR gather (k in [0, KD1)); 8 threads/row ----
  {
    int gr = tid >> 3;
    int gj = tid & 7;
    int grow = row0 + gr;
    if (grow >= M) grow = M - 1;
    const float4* fbase = (const float4*)feat + gj * CPT;
    int e0 = rs[grow], e1 = rs[grow + 1];
    f32x4 s[CPT];
#pragma unroll
    for (int j = 0; j < CPT; ++j) s[j] = (f32x4){0.f, 0.f, 0.f, 0.f};
    int e = e0;
    for (; e + 3 < e1; e += 4) {
      int c0 = csr[e], c1 = csr[e + 1], c2 = csr[e + 2], c3 = csr[e + 3];
      const float4* p0 = fbase + (size_t)c0 * (KD1 / 4);
      const float4* p1 = fbase + (size_t)c1 * (KD1 / 4);
      const float4* p2 = fbase + (size_t)c2 * (KD1 / 4);
      const float4* p3 = fbase + (size_t)c3 * (KD1 / 4);
      float4 v0[CPT], v1[CPT], v2[CPT], v3[CPT];
#pragma unroll
      for (int j = 0; j < CPT; ++j) { v0[j] = p0[j]; v1[j] = p1[j]; v2[j] = p2[j]; v3[j] = p3[j]; }
#pragma unroll
      for (int j = 0; j < CPT; ++j) {
        s[j] += (f32x4){v0[j].x, v0[j].y, v0[j].z, v0[j].w};
        s[j] += (f32x4){v1[j].x, v1[j].y, v1[j].z, v1[j].w};
        s[j] += (f32x4){v2[j].x, v2[j].y, v2[j].z, v2[j].w};
        s[j] += (f32x4){v3[j].x, v3[j].y, v3[j].z, v3[j].w};
      }
    }
    for (; e < e1; ++e) {
      const float4* p = fbase + (size_t)csr[e] * (KD1 / 4);
#pragma unroll
      for (int j = 0; j < CPT; ++j) {
        float4 v = p[j];
        s[j] += (f32x4){v.x, v.y, v.z, v.w};
      }
    }
    int base = (gr * KTOT + gj * CPT * 4) * 2;
    int sw = (gr & 7) << 4;
#pragma unroll
    for (int h = 0; h < CPT / 2; ++h) {
      half8 vh, vl;
#pragma unroll
      for (int j = 0; j < 8; ++j) {
        float f = s[h * 2 + (j >> 2)][j & 3];
        _Float16 hi = (_Float16)f;
        vh[j] = hi;
        vl[j] = (_Float16)(f - (float)hi);
      }
      int byte = (base + h * 16) ^ sw;
      *(half8*)((char*)ah_lds + byte) = vh;
      *(half8*)((char*)al_lds + byte) = vl;
    }
  }

  // ---- Phase 1b: root staging (k in [KD1, KTOT)) ----
  for (int idx = tid; idx < 64 * KD2 / 8; idx += 512) {
    int row = idx / (KD2 / 8);
    int kc = (idx % (KD2 / 8)) * 8;
    int grow = row0 + row;
    if (grow >= M) grow = M - 1;
    const float* sp = xr + (size_t)grow * KD2 + kc;
    float4 a0 = *(const float4*)sp;
    float4 a1 = *(const float4*)(sp + 4);
    float av[8] = {a0.x, a0.y, a0.z, a0.w, a1.x, a1.y, a1.z, a1.w};
    half8 vh, vl;
#pragma unroll
    for (int j = 0; j < 8; ++j) {
      _Float16 h = (_Float16)av[j];
      vh[j] = h;
      vl[j] = (_Float16)(av[j] - (float)h);
    }
    int byte = ((row * KTOT + KD1 + kc) * 2) ^ ((row & 7) << 4);
    *(half8*)((char*)ah_lds + byte) = vh;
    *(half8*)((char*)al_lds + byte) = vl;
  }

  // issue first W step before the barrier (latency hides under barrier wait)
  size_t wbase = (size_t)(ch0 + col) * KTOT + kseg;
  half8 whc = *(const half8*)(Wh + wbase);
  half8 wlc = *(const half8*)(Wl + wbase);
  __syncthreads();

  // ---- Phase 2: k-loop; W double-buffered from L2, A from LDS ----
  f32x4 acc[4];
#pragma unroll
  for (int rf = 0; rf < 4; ++rf) acc[rf] = (f32x4){0.f, 0.f, 0.f, 0.f};
  int r = lane & 15;
#pragma unroll
  for (int s = 0; s < NSTEP; ++s) {
    half8 whn, wln;
    if (s + 1 < NSTEP) {  // compile-time after unroll
      whn = *(const half8*)(Wh + wbase + (s + 1) * 32);
      wln = *(const half8*)(Wl + wbase + (s + 1) * 32);
    }
#pragma unroll
    for (int rf = 0; rf < 4; ++rf) {
      int row = rf * 16 + r;
      int byte = ((row * KTOT + s * 32 + kseg) * 2) ^ ((row & 7) << 4);
      half8 a_h = *(const half8*)((const char*)ah_lds + byte);
      half8 a_l = *(const half8*)((const char*)al_lds + byte);
      acc[rf] = __builtin_amdgcn_mfma_f32_16x16x32_f16(a_l, whc, acc[rf], 0, 0, 0);
      acc[rf] = __builtin_amdgcn_mfma_f32_16x16x32_f16(a_h, wlc, acc[rf], 0, 0, 0);
      acc[rf] = __builtin_amdgcn_mfma_f32_16x16x32_f16(a_h, whc, acc[rf], 0, 0, 0);
    }
    if (s + 1 < NSTEP) { whc = whn; wlc = wln; }
  }

  // ---- epilogue: bias + relu (+ pool partials / score) ----
  float bv = bias[ch0 + col];
  float cmax = -3.402823466e38f, csum = 0.f;
  float wcol = SCORE ? pw[ch0 + col] : 0.f;
  float pd[4][4];
  int g = 0, rowbase = 0;
  if (POOL == 2) { g = row0 / KKP; rowbase = row0 - g * KKP; }
#pragma unroll
  for (int rf = 0; rf < 4; ++rf) {
    int orow0 = row0 + rf * 16 + (lane >> 4) * 4;
#pragma unroll
    for (int rr = 0; rr < 4; ++rr) {
      int orow = orow0 + rr;
      float v = fmaxf(acc[rf][rr] + bv, 0.f);
      if (orow < M) out[(size_t)orow * HH + ch0 + col] = v;
      if (POOL == 1) { cmax = fmaxf(cmax, v); csum += v; }
      if (POOL == 2) {
        int local = rowbase + rf * 16 + (lane >> 4) * 4 + rr;
        if (local < KK) { cmax = fmaxf(cmax, v); csum += v; }
      }
      if (SCORE) pd[rf][rr] = v * wcol;
    }
  }
  if (POOL) {
    cmax = fmaxf(cmax, __shfl_xor(cmax, 16, 64)); csum += __shfl_xor(csum, 16, 64);
    cmax = fmaxf(cmax, __shfl_xor(cmax, 32, 64)); csum += __shfl_xor(csum, 32, 64);
    if ((lane >> 4) == 0) {
      if (POOL == 1) {
        int gg = row0 >> 11, sb = (row0 & 2047) >> 6;  // 32 slices of 64 rows
        pmax[(gg * 32 + sb) * HH + ch0 + col] = cmax;
        psum[(gg * 32 + sb) * HH + ch0 + col] = csum;
      } else {
        int sb = rowbase >> 6;                          // 26 slices of 64 rows
        pmax[(g * 26 + sb) * HH + ch0 + col] = cmax;
        psum[(g * 26 + sb) * HH + ch0 + col] = csum;
      }
    }
  }
  if (SCORE) {
    // reduce each pd over the 16 cols (lanes differing in bits 0..3 share a row)
#pragma unroll
    for (int rf = 0; rf < 4; ++rf)
#pragma unroll
      for (int rr = 0; rr < 4; ++rr) {
        float d = pd[rf][rr];
        d += __shfl_xor(d, 1, 64); d += __shfl_xor(d, 2, 64);
        d += __shfl_xor(d, 4, 64); d += __shfl_xor(d, 8, 64);
        if (col == 0) sdot[rf * 16 + (lane >> 4) * 4 + rr][wid] = d;
      }
    float wsq = wcol * wcol;
    wsq += __shfl_xor(wsq, 1, 64); wsq += __shfl_xor(wsq, 2, 64);
    wsq += __shfl_xor(wsq, 4, 64); wsq += __shfl_xor(wsq, 8, 64);
    if (lane == 0) swsq[wid] = wsq;
    __syncthreads();
    if (tid < 64) {
      float d = 0.f, q = 0.f;
#pragma unroll
      for (int wv = 0; wv < 8; ++wv) { d += sdot[tid][wv]; q += swsq[wv]; }
      score[row0 + tid] = tanhf(d * rsqrtf(q));
    }
  }
}

// ---------------- weight prep: split Wcat[o][k] into f16 hi + lo planes ----------------
__global__ void prep_weights_f16(const float* __restrict__ W1_rel, const float* __restrict__ W1_root,
                                 const float* __restrict__ W2_rel, const float* __restrict__ W2_root,
                                 const float* __restrict__ W3_rel, const float* __restrict__ W3_root,
                                 _Float16* wh1, _Float16* wl1, _Float16* wh2, _Float16* wl2,
                                 _Float16* wh3, _Float16* wl3) {
  int idx = blockIdx.x * blockDim.x + threadIdx.x;
  float v;
  _Float16* ph;
  _Float16* pl;
  int j;
  if (idx < 128 * 128) {
    j = idx;
    int o = j >> 7, k = j & 127;
    v = (k < 64) ? W1_rel[o * 64 + k] : W1_root[o * 64 + (k - 64)];
    ph = wh1; pl = wl1;
  } else if (idx < 128 * 128 + 128 * 256) {
    j = idx - 128 * 128;
    int o = j >> 8, k = j & 255;
    v = (k < 128) ? W2_rel[o * 128 + k] : W2_root[o * 128 + (k - 128)];
    ph = wh2; pl = wl2;
  } else if (idx < 128 * 128 + 2 * 128 * 256) {
    j = idx - 128 * 128 - 128 * 256;
    int o = j >> 8, k = j & 255;
    v = (k < 128) ? W3_rel[o * 128 + k] : W3_root[o * 128 + (k - 128)];
    ph = wh3; pl = wl3;
  } else {
    return;
  }
  _Float16 h = (_Float16)v;
  ph[j] = h;
  pl[j] = (_Float16)(v - (float)h);
}

// per-graph bitonic sort of 2048 (score,index) keys; keep top K, tie-break lowest index
__global__ void topk_kernel(const float* __restrict__ score, int* perm) {
  __shared__ unsigned long long k[NN];
  int b = blockIdx.x;
  int tid = threadIdx.x;  // 1024
  for (int i = tid; i < NN; i += 1024) {
    float s = score[b * NN + i];
    unsigned u = __float_as_uint(s);
    u = (u & 0x80000000u) ? ~u : (u | 0x80000000u);
    unsigned long long key = ((unsigned long long)u << 32) | (unsigned)(NN - 1 - i);
    k[i] = ~key;
  }
  __syncthreads();
  for (int kk = 2; kk <= NN; kk <<= 1) {
    for (int j = kk >> 1; j > 0; j >>= 1) {
      for (int t = tid; t < NN; t += 1024) {
        int ixj = t ^ j;
        if (ixj > t) {
          bool up = ((t & kk) == 0);
          unsigned long long a = k[t], c = k[ixj];
          if ((a > c) == up) { k[t] = c; k[ixj] = a; }
        }
      }
      __syncthreads();
    }
  }
  for (int j = tid; j < KK; j += 1024) {
    unsigned long long key = ~k[j];
    int i = (NN - 1) - (int)(key & 0xffffffffu);
    perm[b * KK + j] = b * NN + i;
  }
}

// fused: gather kept rows, scale by score, write new_id (padded ids), x2 pool partials.
// grid = BG x 13 slices of 128 rows; 128 threads (thread = col).
__global__ void h3pool_kernel(const float* __restrict__ h2, const int* __restrict__ perm,
                              const float* __restrict__ score, float* __restrict__ h3,
                              int* __restrict__ new_id, float* __restrict__ pmax,
                              float* __restrict__ psum) {
  int b = blockIdx.x / 13, s = blockIdx.x % 13;
  int t = threadIdx.x;
  int j0 = s * 128, j1 = min(j0 + 128, KK);
  float m = -3.402823466e38f, sum = 0.f;
  for (int j = j0; j < j1; ++j) {
    int p = perm[b * KK + j];
    if (t == 0) new_id[p] = b * KKP + j;
    float sc = score[p];
    float v = h2[(size_t)p * HH + t] * sc;
    h3[(size_t)(b * KKP + j) * HH + t] = v;
    m = fmaxf(m, v);
    sum += v;
  }
  pmax[(b * 13 + s) * HH + t] = m;
  psum[(b * 13 + s) * HH + t] = sum;
}

// ---------------- final: pool-final x3 + MLP + log_softmax ----------------
__global__ void mlp_kernel(const float* __restrict__ pm1, const float* __restrict__ ps1,
                           const float* __restrict__ pm2, const float* __restrict__ ps2,
                           const float* __restrict__ pm3, const float* __restrict__ ps3,
                           const float* __restrict__ Wl1, const float* __restrict__ bl1,
                           const float* __restrict__ Wl2, const float* __restrict__ bl2,
                           const float* __restrict__ Wl3, const float* __restrict__ bl3,
                           float* out) {
  __shared__ float z[256], a1[128], a2[64], a3[10], red[2];
  int b = blockIdx.x, t = threadIdx.x;  // 128 threads
  float m1 = -3.402823466e38f, m2 = m1, m3 = m1;
  float s1 = 0.f, s2 = 0.f, s3 = 0.f;
  for (int s = 0; s < 32; ++s) {  // x1: 32 slices (conv1 fused pool)
    int o = (b * 32 + s) * 128 + t;
    m1 = fmaxf(m1, pm1[o]); s1 += ps1[o];
  }
  for (int s = 0; s < 13; ++s) {  // x2: 13 slices (h3pool)
    int o = (b * 13 + s) * 128 + t;
    m2 = fmaxf(m2, pm2[o]); s2 += ps2[o];
  }
  for (int s = 0; s < 26; ++s) {  // x3: 26 slices (conv3 fused pool)
    int o = (b * 26 + s) * 128 + t;
    m3 = fmaxf(m3, pm3[o]); s3 += ps3[o];
  }
  z[t] = m1 + m2 + m3;
  z[128 + t] = s1 * (1.f / NN) + (s2 + s3) * (1.f / KK);
  __syncthreads();
  {
    float acc = bl1[t];
    for (int q = 0; q < 256; ++q) acc = fmaf(Wl1[t * 256 + q], z[q], acc);
    a1[t] = fmaxf(acc, 0.f);
  }
  __syncthreads();
  if (t < 64) {
    float acc = bl2[t];
    for (int q = 0; q < 128; ++q) acc = fmaf(Wl2[t * 128 + q], a1[q], acc);
    a2[t] = fmaxf(acc, 0.f);
  }
  __syncthreads();
  if (t < 10) {
    float acc = bl3[t];
    for (int q = 0; q < 64; ++q) acc = fmaf(Wl3[t * 64 + q], a2[q], acc);
    a3[t] = acc;
  }
  __syncthreads();
  if (t == 0) {
    float m = a3[0];
    for (int i = 1; i < 10; ++i) m = fmaxf(m, a3[i]);
    float s = 0.f;
    for (int i = 0; i < 10; ++i) s += expf(a3[i] - m);
    red[0] = m;
    red[1] = logf(s);
  }
  __syncthreads();
  if (t < 10) out[b * 10 + t] = a3[t] - red[0] - red[1];
}

extern "C" void kernel_launch(void* const* d_in, const int* in_sizes, int n_in,
                              void* d_out, int out_size, void* d_ws, size_t ws_size,
                              hipStream_t stream) {
  const float* x       = (const float*)d_in[0];
  const int*   src     = (const int*)d_in[1];
  const int*   dst     = (const int*)d_in[2];
  const float* W1_rel  = (const float*)d_in[3];
  const float* b1      = (const float*)d_in[4];
  const float* W1_root = (const float*)d_in[5];
  const float* W2_rel  = (const float*)d_in[6];
  const float* b2      = (const float*)d_in[7];
  const float* W2_root = (const float*)d_in[8];
  const float* W3_rel  = (const float*)d_in[9];
  const float* b3      = (const float*)d_in[10];
  const float* W3_root = (const float*)d_in[11];
  const float* pool_w  = (const float*)d_in[12];
  const float* Wl1     = (const float*)d_in[13];
  const float* bl1     = (const float*)d_in[14];
  const float* Wl2     = (const float*)d_in[15];
  const float* bl2     = (const float*)d_in[16];
  const float* Wl3     = (const float*)d_in[17];
  const float* bl3     = (const float*)d_in[18];
  float* out = (float*)d_out;

  // workspace layout
  char* w = (char*)d_ws;
  size_t off = 0;
  auto alloc = [&](size_t bytes) -> char* {
    off = (off + 255) & ~(size_t)255;
    char* p = w + off;
    off += bytes;
    return p;
  };
  // deg1 | deg2 contiguous (one memset); +4096 ints pad for exscan int4 tiles
  int* degs     = (int*)alloc((NB + N1P + 4096) * 4);
  int* deg1     = degs;
  int* deg2     = degs + NB;
  int* rs1      = (int*)alloc((NB + 1) * 4);
  int* cursor1  = (int*)alloc(NB * 4);
  int* csr1     = (int*)alloc((size_t)EE * 4);
  int* rs2      = (int*)alloc((N1P + 1) * 4);
  int* cursor2  = (int*)alloc(N1P * 4);
  int* csr2     = (int*)alloc((size_t)EE * 4);
  int* new_id   = (int*)alloc(NB * 4);
  int* perm     = (int*)alloc(N1 * 4);
  _Float16* wh1 = (_Float16*)alloc(128 * 128 * 2);
  _Float16* wl1 = (_Float16*)alloc(128 * 128 * 2);
  _Float16* wh2 = (_Float16*)alloc(128 * 256 * 2);
  _Float16* wl2 = (_Float16*)alloc(128 * 256 * 2);
  _Float16* wh3 = (_Float16*)alloc(128 * 256 * 2);
  _Float16* wl3 = (_Float16*)alloc(128 * 256 * 2);
  float* bufA   = (float*)alloc((size_t)NB * HH * 4);  // h1, then h3 (padded rows)
  float* bufB   = (float*)alloc((size_t)NB * HH * 4);  // h2, then h4 (padded rows)
  float* score  = (float*)alloc(NB * 4);
  float* pm1    = (float*)alloc(BG * 32 * HH * 4);
  float* ps1    = (float*)alloc(BG * 32 * HH * 4);
  float* pm2    = (float*)alloc(BG * 13 * HH * 4);
  float* ps2    = (float*)alloc(BG * 13 * HH * 4);
  float* pm3    = (float*)alloc(BG * 26 * HH * 4);
  float* ps3    = (float*)alloc(BG * 26 * HH * 4);
  if (off > ws_size) return;  // workspace too small: fail visibly

  const int TB = 256;
  const int egrid = (EE + TB - 1) / TB;

  hipMemsetAsync(degs, 0, (NB + N1P + 4096) * 4, stream);
  hipMemsetAsync(new_id, 0xFF, NB * 4, stream);  // -1

  prep_weights_f16<<<(128 * 128 + 2 * 128 * 256 + TB - 1) / TB, TB, 0, stream>>>(
      W1_rel, W1_root, W2_rel, W2_root, W3_rel, W3_root, wh1, wl1, wh2, wl2, wh3, wl3);

  // CSR1 (src -> dst)
  deg_kernel<<<egrid, TB, 0, stream>>>(dst, deg1, EE);
  exscan_kernel<<<1, 1024, 0, stream>>>(deg1, rs1, cursor1, NB);
  scatter_kernel<<<egrid, TB, 0, stream>>>(src, dst, cursor1, csr1, EE);

  // conv1: gather + GEMM + x1 pool fused
  conv_mfma<64, 64, 1, 0><<<NB / 64, 512, 0, stream>>>(
      x, x, rs1, csr1, wh1, wl1, b1, bufA, NB, NB / 64, pm1, ps1, nullptr, nullptr);

  // conv2: gather + GEMM + score fused
  conv_mfma<128, 128, 0, 1><<<NB / 64, 512, 0, stream>>>(
      bufA, bufA, rs1, csr1, wh2, wl2, b2, bufB, NB, NB / 64, nullptr, nullptr, pool_w, score);

  // topk + fused h3/new_id/x2-pool
  topk_kernel<<<BG, 1024, 0, stream>>>(score, perm);
  h3pool_kernel<<<BG * 13, 128, 0, stream>>>(bufB, perm, score, bufA, new_id, pm2, ps2);

  // CSR2 over remapped kept edges (padded id space)
  deg2_kernel<<<egrid, TB, 0, stream>>>(src, dst, new_id, deg2, EE);
  exscan_kernel<<<1, 1024, 0, stream>>>(deg2, rs2, cursor2, N1P);
  scatter2_kernel<<<egrid, TB, 0, stream>>>(src, dst, new_id, cursor2, csr2, EE);

  // conv3: gather + GEMM + x3 pool fused (padded rows masked)
  conv_mfma<128, 128, 2, 0><<<N1P / 64, 512, 0, stream>>>(
      bufA, bufA, rs2, csr2, wh3, wl3, b3, bufB, N1P, N1P / 64, pm3, ps3, nullptr, nullptr);

  // pool finals + MLP head + log_softmax (fused)
  mlp_kernel<<<BG, 128, 0, stream>>>(pm1, ps1, pm2, ps2, pm3, ps3,
                                     Wl1, bl1, Wl2, bl2, Wl3, bl3, out);
}

// Round 11
// 275.022 us; speedup vs baseline: 1.3268x; 1.0602x over previous
//
#include <hip/hip_runtime.h>
#include <hip/hip_bf16.h>
#include <math.h>

#define NB 32768      // total nodes (B*N)
#define NN 2048       // nodes per graph
#define BG 16         // graphs
#define KK 1639       // kept per graph (0.8*2048 ceil)
#define KKP 1664      // kept rows padded to 64*26 = 13*128
#define N1 (BG*KK)    // 26224 real kept nodes
#define N1P (BG*KKP)  // 26624 padded kept rows
#define EE 524288     // total edges
#define HH 128        // hidden
#define FIN 64        // input features

using half8 = __attribute__((ext_vector_type(8))) _Float16;
using f32x4 = __attribute__((ext_vector_type(4))) float;

// ---------------- CSR build ----------------
__global__ void deg_kernel(const int* __restrict__ dst, int* deg, int n) {
  int e = blockIdx.x * blockDim.x + threadIdx.x;
  if (e < n) atomicAdd(&deg[dst[e]], 1);
}

__global__ void deg2_kernel(const int* __restrict__ src, const int* __restrict__ dst,
                            const int* __restrict__ new_id, int* deg, int n) {
  int e = blockIdx.x * blockDim.x + threadIdx.x;
  if (e < n) {
    int a = new_id[src[e]], d = new_id[dst[e]];
    if (a >= 0 && d >= 0) atomicAdd(&deg[d], 1);
  }
}

// single-block coalesced exclusive scan (int4 tiles of 4096); deg must be padded.
__global__ void exscan_kernel(const int* __restrict__ deg, int* rs, int* cursor, int n) {
  __shared__ int wsum[16];
  __shared__ int carry;
  int t = threadIdx.x;  // 1024
  int lane = t & 63, wid = t >> 6;
  if (t == 0) carry = 0;
  __syncthreads();
  int ntiles = (n + 4095) >> 12;
  for (int tile = 0; tile < ntiles; ++tile) {
    int idx = (tile << 12) + t * 4;
    int4 v4 = *(const int4*)(deg + idx);
    int v0 = (idx + 0 < n) ? v4.x : 0;
    int v1 = (idx + 1 < n) ? v4.y : 0;
    int v2 = (idx + 2 < n) ? v4.z : 0;
    int v3 = (idx + 3 < n) ? v4.w : 0;
    int s = v0 + v1 + v2 + v3;
    int pre = s;
#pragma unroll
    for (int off = 1; off < 64; off <<= 1) {
      int u = __shfl_up(pre, off, 64);
      if (lane >= off) pre += u;
    }
    if (lane == 63) wsum[wid] = pre;
    __syncthreads();
    int wbase = 0;
#pragma unroll
    for (int ww = 0; ww < 16; ++ww)
      if (ww < wid) wbase += wsum[ww];
    int ex = carry + wbase + (pre - s);
    int4 e4 = make_int4(ex, ex + v0, ex + v0 + v1, ex + v0 + v1 + v2);
    if (idx + 3 < n) {
      *(int4*)(rs + idx) = e4;
      *(int4*)(cursor + idx) = e4;
    } else {
      if (idx + 0 < n) { rs[idx + 0] = e4.x; cursor[idx + 0] = e4.x; }
      if (idx + 1 < n) { rs[idx + 1] = e4.y; cursor[idx + 1] = e4.y; }
      if (idx + 2 < n) { rs[idx + 2] = e4.z; cursor[idx + 2] = e4.z; }
    }
    int tot = 0;
    if (t == 1023) tot = ex + s;
    __syncthreads();
    if (t == 1023) carry = tot;
    __syncthreads();
  }
  if (t == 0) rs[n] = carry;
}

__global__ void scatter_kernel(const int* __restrict__ src, const int* __restrict__ dst,
                               int* cursor, int* csr, int n) {
  int e = blockIdx.x * blockDim.x + threadIdx.x;
  if (e < n) {
    int d = dst[e];
    int p = atomicAdd(&cursor[d], 1);
    csr[p] = src[e];
  }
}

__global__ void scatter2_kernel(const int* __restrict__ src, const int* __restrict__ dst,
                                const int* __restrict__ new_id, int* cursor, int* csr, int n) {
  int e = blockIdx.x * blockDim.x + threadIdx.x;
  if (e < n) {
    int a = new_id[src[e]], d = new_id[dst[e]];
    if (a >= 0 && d >= 0) {
      int p = atomicAdd(&cursor[d], 1);
      csr[p] = a;
    }
  }
}

// ---------------- fused agg + conv GEMM (+optional pool / score epilogues) ----------------
// out = relu([agg|x] @ Wcat^T + b); agg gathered in-kernel from CSR.
// 512 thr = 8 waves; tile = 64 rows x 128 cols; wave = 64x16 (4 row frags).
// Phase 1: CSR gather (8 thr/row, x4 edge unroll) + root staging -> f16 hi/lo
//   XOR-swizzled LDS planes. Phase 2: k-loop = ds_read + MFMA with W double-
//   buffered from L2 (16 VGPR window, no stationary 64-VGPR set).
// POOL=1: x1-pool partials (2048 rows/graph, 32 slices). POOL=2: x3-pool
//   partials (1664 rows/graph padded, 26 slices, rows >=1639 masked).
// SCORE=1: per-row tanh(dot(h,w)/||w||) via shfl col-reduce + LDS cross-wave.
template <int KD1, int KD2, int POOL, int SCORE>
__global__ __launch_bounds__(512, 4) void conv_mfma(
    const float* __restrict__ feat, const float* __restrict__ xr,
    const int* __restrict__ rs, const int* __restrict__ csr,
    const _Float16* __restrict__ Wh, const _Float16* __restrict__ Wl,
    const float* __restrict__ bias, float* __restrict__ out, int M, int nwg,
    float* __restrict__ pmax, float* __restrict__ psum,
    const float* __restrict__ pw, float* __restrict__ score) {
  constexpr int KTOT = KD1 + KD2;
  constexpr int NSTEP = KTOT / 32;
  constexpr int CPT = KD1 / 32;   // float4 chunks per gather thread
  __shared__ _Float16 ah_lds[64 * KTOT];
  __shared__ _Float16 al_lds[64 * KTOT];
  __shared__ float sdot[64][8];
  __shared__ float swsq[8];

  int tid = threadIdx.x;
  int lane = tid & 63, wid = tid >> 6;
  // bijective XCD-chunk swizzle (m204)
  int bq = nwg >> 3, br = nwg & 7, bx = blockIdx.x & 7, bi = blockIdx.x >> 3;
  int swz = (bx < br ? bx * (bq + 1) : br * (bq + 1) + (bx - br) * bq) + bi;
  int row0 = swz * 64;
  int ch0 = wid * 16;
  int col = lane & 15;
  int kseg = (lane >> 4) * 8;

  // ---- Phase 1a: CSR gather (k in [0, KD1)); 8 threads/row ----
  {
    int gr = tid >> 3;
    int gj = tid & 7;
    int grow = row0 + gr;
    if (grow >= M) grow = M - 1;
    const float4* fbase = (const float4*)feat + gj * CPT;
    int e0 = rs[grow], e1 = rs[grow + 1];
    f32x4 s[CPT];
#pragma unroll
    for (int j = 0; j < CPT; ++j) s[j] = (f32x4){0.f, 0.f, 0.f, 0.f};
    int e = e0;
    for (; e + 3 < e1; e += 4) {
      int c0 = csr[e], c1 = csr[e + 1], c2 = csr[e + 2], c3 = csr[e + 3];
      const float4* p0 = fbase + (size_t)c0 * (KD1 / 4);
      const float4* p1 = fbase + (size_t)c1 * (KD1 / 4);
      const float4* p2 = fbase + (size_t)c2 * (KD1 / 4);
      const float4* p3 = fbase + (size_t)c3 * (KD1 / 4);
      float4 v0[CPT], v1[CPT], v2[CPT], v3[CPT];
#pragma unroll
      for (int j = 0; j < CPT; ++j) { v0[j] = p0[j]; v1[j] = p1[j]; v2[j] = p2[j]; v3[j] = p3[j]; }
#pragma unroll
      for (int j = 0; j < CPT; ++j) {
        s[j] += (f32x4){v0[j].x, v0[j].y, v0[j].z, v0[j].w};
        s[j] += (f32x4){v1[j].x, v1[j].y, v1[j].z, v1[j].w};
        s[j] += (f32x4){v2[j].x, v2[j].y, v2[j].z, v2[j].w};
        s[j] += (f32x4){v3[j].x, v3[j].y, v3[j].z, v3[j].w};
      }
    }
    for (; e < e1; ++e) {
      const float4* p = fbase + (size_t)csr[e] * (KD1 / 4);
#pragma unroll
      for (int j = 0; j < CPT; ++j) {
        float4 v = p[j];
        s[j] += (f32x4){v.x, v.y, v.z, v.w};
      }
    }
    int base = (gr * KTOT + gj * CPT * 4) * 2;
    int sw = (gr & 7) << 4;
#pragma unroll
    for (int h = 0; h < CPT / 2; ++h) {
      half8 vh, vl;
#pragma unroll
      for (int j = 0; j < 8; ++j) {
        float f = s[h * 2 + (j >> 2)][j & 3];
        _Float16 hi = (_Float16)f;
        vh[j] = hi;
        vl[j] = (_Float16)(f - (float)hi);
      }
      int byte = (base + h * 16) ^ sw;
      *(half8*)((char*)ah_lds + byte) = vh;
      *(half8*)((char*)al_lds + byte) = vl;
    }
  }

  // ---- Phase 1b: root staging (k in [KD1, KTOT)) ----
  for (int idx = tid; idx < 64 * KD2 / 8; idx += 512) {
    int row = idx / (KD2 / 8);
    int kc = (idx % (KD2 / 8)) * 8;
    int grow = row0 + row;
    if (grow >= M) grow = M - 1;
    const float* sp = xr + (size_t)grow * KD2 + kc;
    float4 a0 = *(const float4*)sp;
    float4 a1 = *(const float4*)(sp + 4);
    float av[8] = {a0.x, a0.y, a0.z, a0.w, a1.x, a1.y, a1.z, a1.w};
    half8 vh, vl;
#pragma unroll
    for (int j = 0; j < 8; ++j) {
      _Float16 h = (_Float16)av[j];
      vh[j] = h;
      vl[j] = (_Float16)(av[j] - (float)h);
    }
    int byte = ((row * KTOT + KD1 + kc) * 2) ^ ((row & 7) << 4);
    *(half8*)((char*)ah_lds + byte) = vh;
    *(half8*)((char*)al_lds + byte) = vl;
  }

  // issue first W step before the barrier (latency hides under barrier wait)
  size_t wbase = (size_t)(ch0 + col) * KTOT + kseg;
  half8 whc = *(const half8*)(Wh + wbase);
  half8 wlc = *(const half8*)(Wl + wbase);
  __syncthreads();

  // ---- Phase 2: k-loop; W double-buffered from L2, A from LDS ----
  f32x4 acc[4];
#pragma unroll
  for (int rf = 0; rf < 4; ++rf) acc[rf] = (f32x4){0.f, 0.f, 0.f, 0.f};
  int r = lane & 15;
#pragma unroll
  for (int s = 0; s < NSTEP; ++s) {
    half8 whn, wln;
    if (s + 1 < NSTEP) {  // compile-time after unroll
      whn = *(const half8*)(Wh + wbase + (s + 1) * 32);
      wln = *(const half8*)(Wl + wbase + (s + 1) * 32);
    }
#pragma unroll
    for (int rf = 0; rf < 4; ++rf) {
      int row = rf * 16 + r;
      int byte = ((row * KTOT + s * 32 + kseg) * 2) ^ ((row & 7) << 4);
      half8 a_h = *(const half8*)((const char*)ah_lds + byte);
      half8 a_l = *(const half8*)((const char*)al_lds + byte);
      acc[rf] = __builtin_amdgcn_mfma_f32_16x16x32_f16(a_l, whc, acc[rf], 0, 0, 0);
      acc[rf] = __builtin_amdgcn_mfma_f32_16x16x32_f16(a_h, wlc, acc[rf], 0, 0, 0);
      acc[rf] = __builtin_amdgcn_mfma_f32_16x16x32_f16(a_h, whc, acc[rf], 0, 0, 0);
    }
    if (s + 1 < NSTEP) { whc = whn; wlc = wln; }
  }

  // ---- epilogue: bias + relu (+ pool partials / score) ----
  float bv = bias[ch0 + col];
  float cmax = -3.402823466e38f, csum = 0.f;
  float wcol = SCORE ? pw[ch0 + col] : 0.f;
  float pd[4][4];
  int g = 0, rowbase = 0;
  if (POOL == 2) { g = row0 / KKP; rowbase = row0 - g * KKP; }
#pragma unroll
  for (int rf = 0; rf < 4; ++rf) {
    int orow0 = row0 + rf * 16 + (lane >> 4) * 4;
#pragma unroll
    for (int rr = 0; rr < 4; ++rr) {
      int orow = orow0 + rr;
      float v = fmaxf(acc[rf][rr] + bv, 0.f);
      if (orow < M) out[(size_t)orow * HH + ch0 + col] = v;
      if (POOL == 1) { cmax = fmaxf(cmax, v); csum += v; }
      if (POOL == 2) {
        int local = rowbase + rf * 16 + (lane >> 4) * 4 + rr;
        if (local < KK) { cmax = fmaxf(cmax, v); csum += v; }
      }
      if (SCORE) pd[rf][rr] = v * wcol;
    }
  }
  if (POOL) {
    cmax = fmaxf(cmax, __shfl_xor(cmax, 16, 64)); csum += __shfl_xor(csum, 16, 64);
    cmax = fmaxf(cmax, __shfl_xor(cmax, 32, 64)); csum += __shfl_xor(csum, 32, 64);
    if ((lane >> 4) == 0) {
      if (POOL == 1) {
        int gg = row0 >> 11, sb = (row0 & 2047) >> 6;  // 32 slices of 64 rows
        pmax[(gg * 32 + sb) * HH + ch0 + col] = cmax;
        psum[(gg * 32 + sb) * HH + ch0 + col] = csum;
      } else {
        int sb = rowbase >> 6;                          // 26 slices of 64 rows
        pmax[(g * 26 + sb) * HH + ch0 + col] = cmax;
        psum[(g * 26 + sb) * HH + ch0 + col] = csum;
      }
    }
  }
  if (SCORE) {
    // reduce each pd over the 16 cols (lanes differing in bits 0..3 share a row)
#pragma unroll
    for (int rf = 0; rf < 4; ++rf)
#pragma unroll
      for (int rr = 0; rr < 4; ++rr) {
        float d = pd[rf][rr];
        d += __shfl_xor(d, 1, 64); d += __shfl_xor(d, 2, 64);
        d += __shfl_xor(d, 4, 64); d += __shfl_xor(d, 8, 64);
        if (col == 0) sdot[rf * 16 + (lane >> 4) * 4 + rr][wid] = d;
      }
    float wsq = wcol * wcol;
    wsq += __shfl_xor(wsq, 1, 64); wsq += __shfl_xor(wsq, 2, 64);
    wsq += __shfl_xor(wsq, 4, 64); wsq += __shfl_xor(wsq, 8, 64);
    if (lane == 0) swsq[wid] = wsq;
    __syncthreads();
    if (tid < 64) {
      float d = 0.f, q = 0.f;
#pragma unroll
      for (int wv = 0; wv < 8; ++wv) { d += sdot[tid][wv]; q += swsq[wv]; }
      score[row0 + tid] = tanhf(d * rsqrtf(q));
    }
  }
}

// ---------------- weight prep: split Wcat[o][k] into f16 hi + lo planes ----------------
__global__ void prep_weights_f16(const float* __restrict__ W1_rel, const float* __restrict__ W1_root,
                                 const float* __restrict__ W2_rel, const float* __restrict__ W2_root,
                                 const float* __restrict__ W3_rel, const float* __restrict__ W3_root,
                                 _Float16* wh1, _Float16* wl1, _Float16* wh2, _Float16* wl2,
                                 _Float16* wh3, _Float16* wl3) {
  int idx = blockIdx.x * blockDim.x + threadIdx.x;
  float v;
  _Float16* ph;
  _Float16* pl;
  int j;
  if (idx < 128 * 128) {
    j = idx;
    int o = j >> 7, k = j & 127;
    v = (k < 64) ? W1_rel[o * 64 + k] : W1_root[o * 64 + (k - 64)];
    ph = wh1; pl = wl1;
  } else if (idx < 128 * 128 + 128 * 256) {
    j = idx - 128 * 128;
    int o = j >> 8, k = j & 255;
    v = (k < 128) ? W2_rel[o * 128 + k] : W2_root[o * 128 + (k - 128)];
    ph = wh2; pl = wl2;
  } else if (idx < 128 * 128 + 2 * 128 * 256) {
    j = idx - 128 * 128 - 128 * 256;
    int o = j >> 8, k = j & 255;
    v = (k < 128) ? W3_rel[o * 128 + k] : W3_root[o * 128 + (k - 128)];
    ph = wh3; pl = wl3;
  } else {
    return;
  }
  _Float16 h = (_Float16)v;
  ph[j] = h;
  pl[j] = (_Float16)(v - (float)h);
}

// per-graph bitonic sort of 2048 (score,index) keys; keep top K, tie-break lowest index
__global__ void topk_kernel(const float* __restrict__ score, int* perm) {
  __shared__ unsigned long long k[NN];
  int b = blockIdx.x;
  int tid = threadIdx.x;  // 1024
  for (int i = tid; i < NN; i += 1024) {
    float s = score[b * NN + i];
    unsigned u = __float_as_uint(s);
    u = (u & 0x80000000u) ? ~u : (u | 0x80000000u);
    unsigned long long key = ((unsigned long long)u << 32) | (unsigned)(NN - 1 - i);
    k[i] = ~key;
  }
  __syncthreads();
  for (int kk = 2; kk <= NN; kk <<= 1) {
    for (int j = kk >> 1; j > 0; j >>= 1) {
      for (int t = tid; t < NN; t += 1024) {
        int ixj = t ^ j;
        if (ixj > t) {
          bool up = ((t & kk) == 0);
          unsigned long long a = k[t], c = k[ixj];
          if ((a > c) == up) { k[t] = c; k[ixj] = a; }
        }
      }
      __syncthreads();
    }
  }
  for (int j = tid; j < KK; j += 1024) {
    unsigned long long key = ~k[j];
    int i = (NN - 1) - (int)(key & 0xffffffffu);
    perm[b * KK + j] = b * NN + i;
  }
}

// gather kept rows (f4), scale by score, write new_id (padded id space)
__global__ void h3_kernel(const float4* __restrict__ h2, const int* __restrict__ perm,
                          const float* __restrict__ score, float4* __restrict__ h3,
                          int* __restrict__ new_id) {
  int idx = blockIdx.x * blockDim.x + threadIdx.x;  // over N1*32 float4s
  if (idx < N1 * 32) {
    int g = idx >> 5, c = idx & 31;
    int b = g / KK, j = g - b * KK;
    int p = perm[g];
    if (c == 0) new_id[p] = b * KKP + j;
    float s = score[p];
    float4 v = h2[(size_t)p * 32 + c];
    v.x *= s; v.y *= s; v.z *= s; v.w *= s;
    h3[(size_t)(b * KKP + j) * 32 + c] = v;
  }
}

// x2 pool partials over padded h3 layout: BG x 26 slices of 64 rows (<KK masked)
__global__ void pool2_kernel(const float* __restrict__ h, float* pmax, float* psum) {
  int b = blockIdx.x / 26, s = blockIdx.x % 26;
  int f = threadIdx.x;
  int r0 = s * 64, r1 = min(KK, r0 + 64);
  float m = -3.402823466e38f, sum = 0.f;
  for (int r = r0; r < r1; ++r) {
    float v = h[(size_t)(b * KKP + r) * HH + f];
    m = fmaxf(m, v);
    sum += v;
  }
  pmax[(b * 26 + s) * HH + f] = m;
  psum[(b * 26 + s) * HH + f] = sum;
}

// ---------------- final: pool-final x3 + MLP + log_softmax ----------------
__global__ void mlp_kernel(const float* __restrict__ pm1, const float* __restrict__ ps1,
                           const float* __restrict__ pm2, const float* __restrict__ ps2,
                           const float* __restrict__ pm3, const float* __restrict__ ps3,
                           const float* __restrict__ Wl1, const float* __restrict__ bl1,
                           const float* __restrict__ Wl2, const float* __restrict__ bl2,
                           const float* __restrict__ Wl3, const float* __restrict__ bl3,
                           float* out) {
  __shared__ float z[256], a1[128], a2[64], a3[10], red[2];
  int b = blockIdx.x, t = threadIdx.x;  // 128 threads
  float m1 = -3.402823466e38f, m2 = m1, m3 = m1;
  float s1 = 0.f, s2 = 0.f, s3 = 0.f;
  for (int s = 0; s < 32; ++s) {  // x1: 32 slices (conv1 fused pool)
    int o = (b * 32 + s) * 128 + t;
    m1 = fmaxf(m1, pm1[o]); s1 += ps1[o];
  }
  for (int s = 0; s < 26; ++s) {  // x2/x3: 26 slices
    int o = (b * 26 + s) * 128 + t;
    m2 = fmaxf(m2, pm2[o]); s2 += ps2[o];
    m3 = fmaxf(m3, pm3[o]); s3 += ps3[o];
  }
  z[t] = m1 + m2 + m3;
  z[128 + t] = s1 * (1.f / NN) + (s2 + s3) * (1.f / KK);
  __syncthreads();
  {
    float acc = bl1[t];
    for (int q = 0; q < 256; ++q) acc = fmaf(Wl1[t * 256 + q], z[q], acc);
    a1[t] = fmaxf(acc, 0.f);
  }
  __syncthreads();
  if (t < 64) {
    float acc = bl2[t];
    for (int q = 0; q < 128; ++q) acc = fmaf(Wl2[t * 128 + q], a1[q], acc);
    a2[t] = fmaxf(acc, 0.f);
  }
  __syncthreads();
  if (t < 10) {
    float acc = bl3[t];
    for (int q = 0; q < 64; ++q) acc = fmaf(Wl3[t * 64 + q], a2[q], acc);
    a3[t] = acc;
  }
  __syncthreads();
  if (t == 0) {
    float m = a3[0];
    for (int i = 1; i < 10; ++i) m = fmaxf(m, a3[i]);
    float s = 0.f;
    for (int i = 0; i < 10; ++i) s += expf(a3[i] - m);
    red[0] = m;
    red[1] = logf(s);
  }
  __syncthreads();
  if (t < 10) out[b * 10 + t] = a3[t] - red[0] - red[1];
}

extern "C" void kernel_launch(void* const* d_in, const int* in_sizes, int n_in,
                              void* d_out, int out_size, void* d_ws, size_t ws_size,
                              hipStream_t stream) {
  const float* x       = (const float*)d_in[0];
  const int*   src     = (const int*)d_in[1];
  const int*   dst     = (const int*)d_in[2];
  const float* W1_rel  = (const float*)d_in[3];
  const float* b1      = (const float*)d_in[4];
  const float* W1_root = (const float*)d_in[5];
  const float* W2_rel  = (const float*)d_in[6];
  const float* b2      = (const float*)d_in[7];
  const float* W2_root = (const float*)d_in[8];
  const float* W3_rel  = (const float*)d_in[9];
  const float* b3      = (const float*)d_in[10];
  const float* W3_root = (const float*)d_in[11];
  const float* pool_w  = (const float*)d_in[12];
  const float* Wl1     = (const float*)d_in[13];
  const float* bl1     = (const float*)d_in[14];
  const float* Wl2     = (const float*)d_in[15];
  const float* bl2     = (const float*)d_in[16];
  const float* Wl3     = (const float*)d_in[17];
  const float* bl3     = (const float*)d_in[18];
  float* out = (float*)d_out;

  // workspace layout
  char* w = (char*)d_ws;
  size_t off = 0;
  auto alloc = [&](size_t bytes) -> char* {
    off = (off + 255) & ~(size_t)255;
    char* p = w + off;
    off += bytes;
    return p;
  };
  // deg1 | deg2 contiguous (one memset); +4096 ints pad for exscan int4 tiles
  int* degs     = (int*)alloc((NB + N1P + 4096) * 4);
  int* deg1     = degs;
  int* deg2     = degs + NB;
  int* rs1      = (int*)alloc((NB + 1) * 4);
  int* cursor1  = (int*)alloc(NB * 4);
  int* csr1     = (int*)alloc((size_t)EE * 4);
  int* rs2      = (int*)alloc((N1P + 1) * 4);
  int* cursor2  = (int*)alloc(N1P * 4);
  int* csr2     = (int*)alloc((size_t)EE * 4);
  int* new_id   = (int*)alloc(NB * 4);
  int* perm     = (int*)alloc(N1 * 4);
  _Float16* wh1 = (_Float16*)alloc(128 * 128 * 2);
  _Float16* wl1 = (_Float16*)alloc(128 * 128 * 2);
  _Float16* wh2 = (_Float16*)alloc(128 * 256 * 2);
  _Float16* wl2 = (_Float16*)alloc(128 * 256 * 2);
  _Float16* wh3 = (_Float16*)alloc(128 * 256 * 2);
  _Float16* wl3 = (_Float16*)alloc(128 * 256 * 2);
  float* bufA   = (float*)alloc((size_t)NB * HH * 4);  // h1, then h3 (padded rows)
  float* bufB   = (float*)alloc((size_t)NB * HH * 4);  // h2, then h4 (padded rows)
  float* score  = (float*)alloc(NB * 4);
  float* pm1    = (float*)alloc(BG * 32 * HH * 4);
  float* ps1    = (float*)alloc(BG * 32 * HH * 4);
  float* pm2    = (float*)alloc(BG * 26 * HH * 4);
  float* ps2    = (float*)alloc(BG * 26 * HH * 4);
  float* pm3    = (float*)alloc(BG * 26 * HH * 4);
  float* ps3    = (float*)alloc(BG * 26 * HH * 4);
  if (off > ws_size) return;  // workspace too small: fail visibly

  const int TB = 256;
  const int egrid = (EE + TB - 1) / TB;

  hipMemsetAsync(degs, 0, (NB + N1P + 4096) * 4, stream);
  hipMemsetAsync(new_id, 0xFF, NB * 4, stream);  // -1

  prep_weights_f16<<<(128 * 128 + 2 * 128 * 256 + TB - 1) / TB, TB, 0, stream>>>(
      W1_rel, W1_root, W2_rel, W2_root, W3_rel, W3_root, wh1, wl1, wh2, wl2, wh3, wl3);

  // CSR1 (src -> dst)
  deg_kernel<<<egrid, TB, 0, stream>>>(dst, deg1, EE);
  exscan_kernel<<<1, 1024, 0, stream>>>(deg1, rs1, cursor1, NB);
  scatter_kernel<<<egrid, TB, 0, stream>>>(src, dst, cursor1, csr1, EE);

  // conv1: gather + GEMM + x1 pool fused
  conv_mfma<64, 64, 1, 0><<<NB / 64, 512, 0, stream>>>(
      x, x, rs1, csr1, wh1, wl1, b1, bufA, NB, NB / 64, pm1, ps1, nullptr, nullptr);

  // conv2: gather + GEMM + score fused
  conv_mfma<128, 128, 0, 1><<<NB / 64, 512, 0, stream>>>(
      bufA, bufA, rs1, csr1, wh2, wl2, b2, bufB, NB, NB / 64, nullptr, nullptr, pool_w, score);

  // topk; h3 gather (f4, padded ids); x2 pool partials
  topk_kernel<<<BG, 1024, 0, stream>>>(score, perm);
  h3_kernel<<<(N1 * 32 + TB - 1) / TB, TB, 0, stream>>>((const float4*)bufB, perm, score,
                                                        (float4*)bufA, new_id);
  pool2_kernel<<<BG * 26, 128, 0, stream>>>(bufA, pm2, ps2);

  // CSR2 over remapped kept edges (padded id space)
  deg2_kernel<<<egrid, TB, 0, stream>>>(src, dst, new_id, deg2, EE);
  exscan_kernel<<<1, 1024, 0, stream>>>(deg2, rs2, cursor2, N1P);
  scatter2_kernel<<<egrid, TB, 0, stream>>>(src, dst, new_id, cursor2, csr2, EE);

  // conv3: gather + GEMM + x3 pool fused (padded rows masked)
  conv_mfma<128, 128, 2, 0><<<N1P / 64, 512, 0, stream>>>(
      bufA, bufA, rs2, csr2, wh3, wl3, b3, bufB, N1P, N1P / 64, pm3, ps3, nullptr, nullptr);

  // pool finals + MLP head + log_softmax (fused)
  mlp_kernel<<<BG, 128, 0, stream>>>(pm1, ps1, pm2, ps2, pm3, ps3,
                                     Wl1, bl1, Wl2, bl2, Wl3, bl3, out);
}